// Round 11
// baseline (1231.212 us; speedup 1.0000x reference)
//
#include <hip/hip_runtime.h>
#include <hip/hip_bf16.h>

// Problem constants (MinimalEventMamba)
#define BB   4
#define NBC  5
#define HD   64
#define NLAYER 4
#define NFC  10
#define DIM  128
#define DSN  16
#define DCN  4
#define DTRK 4
#define HH   64
#define WWD  64
#define LL   4096
#define MM   (BB*LL)
#define NCHUNK 128
#define CLEN   32
#define TSTEP  16

// ---------------- prep: all weight transposes + zero stats ----------------
__global__ void k_prep_all(const float* __restrict__ in_proj, const float* __restrict__ out_proj,
                           const float* __restrict__ dec1_w, const float* __restrict__ dec2_w,
                           float* __restrict__ wTin, float* __restrict__ wTout,
                           float* __restrict__ wT1, float* __restrict__ wT2,
                           float* __restrict__ stats, float* __restrict__ stats2) {
    int idx = blockIdx.x * blockDim.x + threadIdx.x;
    if (idx < 65536) {
        int n = idx & 255, k = (idx >> 8) & 63, l = idx >> 14;
        wTin[idx] = in_proj[(l << 14) + (n << 6) + k];
    } else if (idx < 98304) {
        int j = idx - 65536;
        int n = j & 63, k = (j >> 6) & 127, l = j >> 13;
        wTout[j] = out_proj[(l << 13) + (n << 7) + k];
    } else if (idx < 135168) {
        int j = idx - 98304;
        int co = j & 63, tap = (j >> 6) % 9, ci = j / 576;
        wT1[j] = dec1_w[co * 576 + ci * 9 + tap];
    } else if (idx < 142848) {
        int j = idx - 135168;
        int tap = j % 12, t2 = j / 12, co = t2 % NFC, ci = t2 / NFC;
        wT2[j] = (tap < 9) ? dec2_w[co * 576 + ci * 9 + tap] : 0.f;
    } else if (idx < 143104) {
        int j = idx - 142848;
        if (j < 128) stats[j] = 0.f; else stats2[j - 128] = 0.f;
    }
}

// ---------------- Encoder conv + fused BN-stat partials ----------------
__global__ void k_enc_conv(const float* __restrict__ x, const float* __restrict__ w,
                           const float* __restrict__ bias, float* __restrict__ out,
                           float* __restrict__ stats) {
    __shared__ float r1[256], r2[256];
    int tid = threadIdx.x;
    int idx = blockIdx.x * 256 + tid;
    int wx = idx & 63;
    int hy = (idx >> 6) & 63;
    int co = (idx >> 12) & 63;
    int b  = idx >> 18;
    float acc = bias[co];
    for (int ci = 0; ci < NBC; ++ci) {
        const float* xin = x + (((long)(b * NBC + ci)) << 12);
        const float* wp  = w + (co * NBC + ci) * 9;
        #pragma unroll
        for (int kh = 0; kh < 3; ++kh) {
            int ih = hy + kh - 1;
            if (ih < 0 || ih >= HH) continue;
            #pragma unroll
            for (int kw = 0; kw < 3; ++kw) {
                int iw = wx + kw - 1;
                if (iw < 0 || iw >= WWD) continue;
                acc += xin[(ih << 6) + iw] * wp[kh * 3 + kw];
            }
        }
    }
    out[idx] = acc;
    r1[tid] = acc; r2[tid] = acc * acc;
    __syncthreads();
    for (int off = 128; off > 0; off >>= 1) {
        if (tid < off) { r1[tid] += r1[tid + off]; r2[tid] += r2[tid + off]; }
        __syncthreads();
    }
    if (tid == 0) {
        atomicAdd(&stats[co], r1[0]);
        atomicAdd(&stats[64 + co], r2[0]);
    }
}

// ---------------- BN+ReLU (inline stats) with LDS transpose: NCHW -> seq [bhw][c] ----------------
__global__ void k_bn_tr_seq(const float* __restrict__ src, const float* __restrict__ stats,
                            const float* __restrict__ g, const float* __restrict__ be,
                            float* __restrict__ tout) {
    __shared__ float s[64 * 65];
    __shared__ float sc[64], sh[64];
    int blk = blockIdx.x;
    int b = blk >> 6;
    int hw0 = (blk & 63) << 6;
    int tid = threadIdx.x;
    if (tid < 64) {
        float m = stats[tid] * (1.f / 16384.f);
        float var = stats[64 + tid] * (1.f / 16384.f) - m * m;
        float ss = g[tid] * rsqrtf(var + 1e-5f);
        sc[tid] = ss; sh[tid] = be[tid] - m * ss;
    }
    for (int i = tid; i < 4096; i += 256) {
        int pix = i & 63, c = i >> 6;
        s[c * 65 + pix] = src[((long)((b << 6) + c) << 12) + hw0 + pix];
    }
    __syncthreads();
    for (int i = tid; i < 4096; i += 256) {
        int c = i & 63, pix = i >> 6;
        float y = s[c * 65 + pix] * sc[c] + sh[c];
        tout[((long)((b << 12) + hw0 + pix) << 6) + c] = fmaxf(y, 0.f);
    }
}

// ---------------- in_proj GEMM: 64-row tiles, N-split -> grid 512 (2 blocks/CU) ----------------
__global__ __launch_bounds__(256, 2) void k_gemm_in2(const float* __restrict__ tin,
                                                     const float* __restrict__ wT,
                                                     float* __restrict__ xz) {
    __shared__ __align__(16) float ts[64 * 68];
    int nh = blockIdx.x & 1;
    long m0 = (long)(blockIdx.x >> 1) << 6;
    int tid = threadIdx.x;
    for (int i = tid; i < 4096; i += 256) {
        int r = i >> 6, k = i & 63;
        ts[r * 68 + k] = tin[(m0 << 6) + i];
    }
    __syncthreads();
    int rg = tid >> 5;              // 8 groups of 8 rows
    int n0 = (nh << 7) + ((tid & 31) << 2);   // 4 cols within the 128-col half
    float acc[8][4] = {};
    for (int k4 = 0; k4 < 16; ++k4) {
        float4 a[8];
        #pragma unroll
        for (int r2 = 0; r2 < 8; ++r2)
            a[r2] = *(const float4*)&ts[((rg << 3) + r2) * 68 + (k4 << 2)];
        #pragma unroll
        for (int kk = 0; kk < 4; ++kk) {
            const float* wr = wT + (((k4 << 2) + kk) << 8) + n0;
            float4 w0 = *(const float4*)&wr[0];
            #pragma unroll
            for (int r2 = 0; r2 < 8; ++r2) {
                float av = (kk == 0) ? a[r2].x : (kk == 1) ? a[r2].y
                         : (kk == 2) ? a[r2].z : a[r2].w;
                acc[r2][0] += av * w0.x; acc[r2][1] += av * w0.y;
                acc[r2][2] += av * w0.z; acc[r2][3] += av * w0.w;
            }
        }
    }
    #pragma unroll
    for (int r2 = 0; r2 < 8; ++r2) {
        long m = m0 + (rg << 3) + r2;
        *(float4*)&xz[(m << 8) + n0] = make_float4(acc[r2][0], acc[r2][1], acc[r2][2], acc[r2][3]);
    }
}

// ---------------- fused out_proj(i) + residual + in_proj(i+1): 64-row, N-split grid 512 ----------------
// Phase A (N=64) computed redundantly by both n-halves (identical values); only nh==0 writes tio.
__global__ __launch_bounds__(256, 2) void k_gemm_oi(const float* __restrict__ gated,
                                                    const float* __restrict__ wTo,
                                                    const float* __restrict__ wTi,
                                                    float* __restrict__ tio,
                                                    float* __restrict__ xz) {
    __shared__ __align__(16) float g_s[64 * 132];
    __shared__ __align__(16) float t_s[64 * 68];
    int nh = blockIdx.x & 1;
    long m0 = (long)(blockIdx.x >> 1) << 6;
    int tid = threadIdx.x;
    for (int i = tid; i < 8192; i += 256) {
        int r = i >> 7, k = i & 127;
        g_s[r * 132 + k] = gated[(m0 << 7) + i];
    }
    __syncthreads();
    // phase A: out_proj + residual -> t_s (both halves); tio write by nh==0 only
    {
        int rg = tid >> 4, cg = tid & 15;
        int n0 = cg << 2;
        float acc[4][4] = {};
        for (int k4 = 0; k4 < 32; ++k4) {
            float4 a[4];
            #pragma unroll
            for (int r2 = 0; r2 < 4; ++r2)
                a[r2] = *(const float4*)&g_s[((rg << 2) + r2) * 132 + (k4 << 2)];
            #pragma unroll
            for (int kk = 0; kk < 4; ++kk) {
                const float* wr = wTo + (((k4 << 2) + kk) << 6) + n0;
                float4 w0 = *(const float4*)&wr[0];
                #pragma unroll
                for (int r2 = 0; r2 < 4; ++r2) {
                    float av = (kk == 0) ? a[r2].x : (kk == 1) ? a[r2].y
                             : (kk == 2) ? a[r2].z : a[r2].w;
                    acc[r2][0] += av * w0.x; acc[r2][1] += av * w0.y;
                    acc[r2][2] += av * w0.z; acc[r2][3] += av * w0.w;
                }
            }
        }
        #pragma unroll
        for (int r2 = 0; r2 < 4; ++r2) {
            long m = m0 + (rg << 2) + r2;
            float4 t0 = *(const float4*)&tio[(m << 6) + n0];
            t0.x += acc[r2][0]; t0.y += acc[r2][1];
            t0.z += acc[r2][2]; t0.w += acc[r2][3];
            if (nh == 0)
                *(float4*)&tio[(m << 6) + n0] = t0;
            *(float4*)&t_s[((rg << 2) + r2) * 68 + n0] = t0;
        }
    }
    __syncthreads();
    // phase B: in_proj of next layer, this block's 128-col half
    {
        int rg = tid >> 5;
        int n0 = (nh << 7) + ((tid & 31) << 2);
        float acc[8][4] = {};
        for (int k4 = 0; k4 < 16; ++k4) {
            float4 a[8];
            #pragma unroll
            for (int r2 = 0; r2 < 8; ++r2)
                a[r2] = *(const float4*)&t_s[((rg << 3) + r2) * 68 + (k4 << 2)];
            #pragma unroll
            for (int kk = 0; kk < 4; ++kk) {
                const float* wr = wTi + (((k4 << 2) + kk) << 8) + n0;
                float4 w0 = *(const float4*)&wr[0];
                #pragma unroll
                for (int r2 = 0; r2 < 8; ++r2) {
                    float av = (kk == 0) ? a[r2].x : (kk == 1) ? a[r2].y
                             : (kk == 2) ? a[r2].z : a[r2].w;
                    acc[r2][0] += av * w0.x; acc[r2][1] += av * w0.y;
                    acc[r2][2] += av * w0.z; acc[r2][3] += av * w0.w;
                }
            }
        }
        #pragma unroll
        for (int r2 = 0; r2 < 8; ++r2) {
            long m = m0 + (rg << 3) + r2;
            *(float4*)&xz[(m << 8) + n0] = make_float4(acc[r2][0], acc[r2][1], acc[r2][2], acc[r2][3]);
        }
    }
}

// ---------------- out_proj GEMM (final layer): 64-row tiles ----------------
__global__ __launch_bounds__(256, 1) void k_gemm_out2(const float* __restrict__ gated,
                                                      const float* __restrict__ wT,
                                                      float* __restrict__ tio) {
    __shared__ __align__(16) float ts[64 * 132];
    long m0 = (long)blockIdx.x << 6;
    int tid = threadIdx.x;
    int rg = tid >> 4;
    int cg = tid & 15;
    for (int i = tid; i < 8192; i += 256) {
        int r2 = i >> 7, k = i & 127;
        ts[r2 * 132 + k] = gated[(m0 << 7) + i];
    }
    __syncthreads();
    float acc[4][4] = {};
    int n0 = cg << 2;
    for (int k4 = 0; k4 < 32; ++k4) {
        float4 a[4];
        #pragma unroll
        for (int r2 = 0; r2 < 4; ++r2)
            a[r2] = *(const float4*)&ts[((rg << 2) + r2) * 132 + (k4 << 2)];
        #pragma unroll
        for (int kk = 0; kk < 4; ++kk) {
            const float* wr = wT + (((k4 << 2) + kk) << 6) + n0;
            float4 w0 = *(const float4*)&wr[0];
            #pragma unroll
            for (int r2 = 0; r2 < 4; ++r2) {
                float av = (kk == 0) ? a[r2].x : (kk == 1) ? a[r2].y
                         : (kk == 2) ? a[r2].z : a[r2].w;
                acc[r2][0] += av * w0.x; acc[r2][1] += av * w0.y;
                acc[r2][2] += av * w0.z; acc[r2][3] += av * w0.w;
            }
        }
    }
    #pragma unroll
    for (int r2 = 0; r2 < 4; ++r2) {
        long m = m0 + (rg << 2) + r2;
        float4 t0 = *(const float4*)&tio[(m << 6) + n0];
        t0.x += acc[r2][0]; t0.y += acc[r2][1];
        t0.z += acc[r2][2]; t0.w += acc[r2][3];
        *(float4*)&tio[(m << 6) + n0] = t0;
    }
}

// ------- x_proj + dwconv+SiLU + dt-softplus + FUSED SCAN PHASE 1 -------
__global__ __launch_bounds__(256, 2) void k_xproj_fused(
        const float* __restrict__ xz, const float* __restrict__ cw,
        const float* __restrict__ cb, const float* __restrict__ Wx,
        const float* __restrict__ dw, const float* __restrict__ dbias,
        const float* __restrict__ A_log,
        float* __restrict__ xi, float* __restrict__ xdbc,
        float* __restrict__ delta, float* __restrict__ Pb, float* __restrict__ Sb) {
    __shared__ float xz_s[35 * 132];     // reused as delta_s after dwconv phase
    __shared__ float xi_s[32 * 132];
    __shared__ float w_s[36 * 132];
    __shared__ float xs[32 * 40];
    __shared__ float cwT[4 * 128];
    __shared__ float cb_s[128];
    long m0 = (long)blockIdx.x << 5;
    int l0 = (int)(m0 & 4095);
    int b = (int)(m0 >> 12);
    int chunk = l0 >> 5;
    int tid = threadIdx.x;

    for (int i = tid; i < 35 * 128; i += 256) {
        int j = i >> 7, k = i & 127;
        int l = l0 - 3 + j;
        float v = 0.f;
        if (l >= 0) v = xz[(m0 - 3 + j) * 256 + k];
        xz_s[j * 132 + k] = v;
    }
    if (tid < 128) cb_s[tid] = cb[tid];
    for (int i = tid; i < 512; i += 256) {
        int kk = i >> 7, di = i & 127;
        cwT[(kk << 7) + di] = cw[(di << 2) + kk];
    }
    for (int i = tid; i < 4608; i += 256) {
        int n = i >> 7, k = i & 127;
        w_s[n * 132 + k] = Wx[i];
    }
    __syncthreads();

    for (int ii = 0; ii < 4; ++ii) {
        int i = tid + (ii << 8);
        int r = i >> 5;
        int d4 = (i & 31) << 2;
        float4 a = *(const float4*)&cb_s[d4];
        #pragma unroll
        for (int kk = 0; kk < 4; ++kk) {
            float4 xv = *(const float4*)&xz_s[(r + kk) * 132 + d4];
            float4 wv = *(const float4*)&cwT[(kk << 7) + d4];
            a.x += xv.x * wv.x; a.y += xv.y * wv.y;
            a.z += xv.z * wv.z; a.w += xv.w * wv.w;
        }
        a.x = a.x / (1.f + __expf(-a.x));
        a.y = a.y / (1.f + __expf(-a.y));
        a.z = a.z / (1.f + __expf(-a.z));
        a.w = a.w / (1.f + __expf(-a.w));
        *(float4*)&xi_s[r * 132 + d4] = a;
        *(float4*)&xi[(m0 + r) * 128 + d4] = a;
    }
    __syncthreads();

    int n = tid & 63;
    int rg = tid >> 6;
    if (n < 36) {
        float acc[8] = {0,0,0,0,0,0,0,0};
        for (int k4 = 0; k4 < 32; ++k4) {
            float4 w4 = *(const float4*)&w_s[n * 132 + (k4 << 2)];
            #pragma unroll
            for (int r = 0; r < 8; ++r) {
                float4 a4 = *(const float4*)&xi_s[((rg << 3) + r) * 132 + (k4 << 2)];
                acc[r] += a4.x * w4.x + a4.y * w4.y + a4.z * w4.z + a4.w * w4.w;
            }
        }
        #pragma unroll
        for (int r = 0; r < 8; ++r) {
            int rr = (rg << 3) + r;
            xdbc[(m0 + rr) * 36 + n] = acc[r];
            xs[rr * 40 + n] = acc[r];
        }
    }
    __syncthreads();

    float* delta_s = xz_s;
    for (int i = tid; i < 4096; i += 256) {
        int r = i >> 7, di = i & 127;
        float v = dbias[di];
        float4 d4 = *(const float4*)&dw[di << 2];
        v += xs[r * 40 + 0] * d4.x + xs[r * 40 + 1] * d4.y
           + xs[r * 40 + 2] * d4.z + xs[r * 40 + 3] * d4.w;
        float sp = (v > 20.f) ? v : log1pf(expf(v));
        delta[(m0 + r) * 128 + di] = sp;
        delta_s[r * 132 + di] = sp;
    }
    __syncthreads();

    {
        int di = tid >> 1;
        int dso = (tid & 1) << 3;
        float4 al0 = *(const float4*)&A_log[(di << 4) + dso];
        float4 al1 = *(const float4*)&A_log[(di << 4) + dso + 4];
        float Av[8] = { -expf(al0.x), -expf(al0.y), -expf(al0.z), -expf(al0.w),
                        -expf(al1.x), -expf(al1.y), -expf(al1.z), -expf(al1.w) };
        float h[8] = {0,0,0,0,0,0,0,0};
        float P[8] = {1,1,1,1,1,1,1,1};
        #pragma unroll 4
        for (int i = 0; i < CLEN; ++i) {
            float d = delta_s[i * 132 + di];
            float u = xi_s[i * 132 + di];
            float du = d * u;
            float4 B0 = *(float4*)&xs[i * 40 + DTRK + dso];
            float4 B1 = *(float4*)&xs[i * 40 + DTRK + dso + 4];
            float a0 = __expf(d * Av[0]); h[0] = a0 * h[0] + du * B0.x; P[0] *= a0;
            float a1 = __expf(d * Av[1]); h[1] = a1 * h[1] + du * B0.y; P[1] *= a1;
            float a2 = __expf(d * Av[2]); h[2] = a2 * h[2] + du * B0.z; P[2] *= a2;
            float a3 = __expf(d * Av[3]); h[3] = a3 * h[3] + du * B0.w; P[3] *= a3;
            float a4 = __expf(d * Av[4]); h[4] = a4 * h[4] + du * B1.x; P[4] *= a4;
            float a5 = __expf(d * Av[5]); h[5] = a5 * h[5] + du * B1.y; P[5] *= a5;
            float a6 = __expf(d * Av[6]); h[6] = a6 * h[6] + du * B1.z; P[6] *= a6;
            float a7 = __expf(d * Av[7]); h[7] = a7 * h[7] + du * B1.w; P[7] *= a7;
        }
        long o = (((long)chunk * BB + b) << 11) + (di << 4) + dso;
        *(float4*)&Pb[o]     = make_float4(P[0], P[1], P[2], P[3]);
        *(float4*)&Pb[o + 4] = make_float4(P[4], P[5], P[6], P[7]);
        *(float4*)&Sb[o]     = make_float4(h[0], h[1], h[2], h[3]);
        *(float4*)&Sb[o + 4] = make_float4(h[4], h[5], h[6], h[7]);
    }
}

// ---------------- scan phase 2 (stitch) and phase 3 (replay+gate) ----------------
__global__ void k_scan_p2(float* Pb, const float* __restrict__ Sb) {
    int t = blockIdx.x * blockDim.x + threadIdx.x;
    int b = t >> 11;
    int s = t & 2047;
    float h = 0.f;
    for (int c = 0; c < NCHUNK; ++c) {
        long idx = (((long)c * BB + b) << 11) + s;
        float p = Pb[idx];
        float sv = Sb[idx];
        Pb[idx] = h;
        h = p * h + sv;
    }
}

__global__ void k_scan_p3(const float* __restrict__ delta, const float* __restrict__ xi,
                          const float* __restrict__ xdbc, const float* __restrict__ A_log,
                          const float* __restrict__ Dp, const float* __restrict__ xz,
                          const float* __restrict__ hin, float* __restrict__ gated) {
    __shared__ float d_s[TSTEP][64];
    __shared__ float u_s[TSTEP][64];
    __shared__ float bc_s[TSTEP][32];
    __shared__ float y_s[TSTEP][64];
    int chunk = blockIdx.x, b = blockIdx.y, half = blockIdx.z;
    int tid = threadIdx.x;
    int dq = tid & 3;
    int dil = tid >> 2;
    int di = (half << 6) + dil;
    float4 al = *(const float4*)&A_log[(di << 4) + (dq << 2)];
    float Av[4] = { -expf(al.x), -expf(al.y), -expf(al.z), -expf(al.w) };
    float Dv = Dp[di];
    long ho = (((long)chunk * BB + b) << 11) + (di << 4) + (dq << 2);
    float4 h4 = *(const float4*)&hin[ho];
    float h[4] = { h4.x, h4.y, h4.z, h4.w };
    long t0 = ((long)b << 12) + (long)chunk * CLEN;

    int srow = tid >> 4, sc4 = (tid & 15) << 2;
    for (int tile = 0; tile < CLEN / TSTEP; ++tile) {
        __syncthreads();
        long ls = t0 + tile * TSTEP + srow;
        *(float4*)&d_s[srow][sc4] = *(const float4*)&delta[(ls << 7) + (half << 6) + sc4];
        *(float4*)&u_s[srow][sc4] = *(const float4*)&xi[(ls << 7) + (half << 6) + sc4];
        if (tid < 128) {
            int r2 = tid >> 3, cc = (tid & 7) << 2;
            long l2 = t0 + tile * TSTEP + r2;
            *(float4*)&bc_s[r2][cc] = *(const float4*)&xdbc[l2 * 36 + DTRK + cc];
        }
        __syncthreads();
        #pragma unroll
        for (int i = 0; i < TSTEP; ++i) {
            float d = d_s[i][dil];
            float u = u_s[i][dil];
            float du = d * u;
            float4 Bv = *(float4*)&bc_s[i][dq << 2];
            float4 Cv = *(float4*)&bc_s[i][16 + (dq << 2)];
            float a0 = __expf(d * Av[0]); h[0] = a0 * h[0] + du * Bv.x;
            float a1 = __expf(d * Av[1]); h[1] = a1 * h[1] + du * Bv.y;
            float a2 = __expf(d * Av[2]); h[2] = a2 * h[2] + du * Bv.z;
            float a3 = __expf(d * Av[3]); h[3] = a3 * h[3] + du * Bv.w;
            float yp = h[0] * Cv.x + h[1] * Cv.y + h[2] * Cv.z + h[3] * Cv.w;
            yp += __shfl_xor(yp, 1);
            yp += __shfl_xor(yp, 2);
            if (dq == 0)
                y_s[i][dil] = yp + u * Dv;
        }
        __syncthreads();
        {
            long l = t0 + tile * TSTEP + srow;
            float4 y4 = *(float4*)&y_s[srow][sc4];
            float4 z4 = *(const float4*)&xz[(l << 8) + DIM + (half << 6) + sc4];
            float4 og;
            og.x = y4.x * (z4.x / (1.f + __expf(-z4.x)));
            og.y = y4.y * (z4.y / (1.f + __expf(-z4.y)));
            og.z = y4.z * (z4.z / (1.f + __expf(-z4.z)));
            og.w = y4.w * (z4.w / (1.f + __expf(-z4.w)));
            *(float4*)&gated[(l << 7) + (half << 6) + sc4] = og;
        }
    }
}

// ---------------- decoder conv1 + fused BN-stat partials ----------------
__global__ __launch_bounds__(256, 1) void k_dec1_new(const float* __restrict__ tin,
                                                     const float* __restrict__ wT,
                                                     const float* __restrict__ bias,
                                                     float* __restrict__ out,
                                                     float* __restrict__ stats2) {
    __shared__ __align__(16) float x_s[64 * 132];
    __shared__ __align__(16) float w_s[4 * 4608];
    int tile = blockIdx.x;
    int b = blockIdx.y;
    int ty0 = (tile >> 3) << 3;
    int tx0 = (tile & 7) << 3;
    int tid = threadIdx.x;
    int wv = tid >> 6;
    int lane = tid & 63;
    int r = lane >> 3;
    int cg = lane & 7;

    for (int i = tid; i < 6400; i += 256) {
        int pl = i >> 6;
        int c = i & 63;
        int py = pl / 10, px = pl - py * 10;
        int ih = ty0 + py - 1, iw = tx0 + px - 1;
        float v = 0.f;
        if (ih >= 0 && ih < HH && iw >= 0 && iw < WWD)
            v = tin[(((long)((b << 12) + (ih << 6) + iw)) << 6) + c];
        x_s[c * 132 + py * 12 + px] = v;
    }
    float* myw = &w_s[wv * 4608];
    const float* gw = wT + (wv * 16) * 576;
    float4 pref[18];
    #pragma unroll
    for (int i = 0; i < 18; ++i)
        pref[i] = *(const float4*)&gw[(i * 64 + lane) * 4];
    #pragma unroll
    for (int i = 0; i < 18; ++i)
        *(float4*)&myw[(i * 64 + lane) * 4] = pref[i];
    __syncthreads();

    float acc[8][8] = {};
    #pragma unroll
    for (int ch = 0; ch < 2; ++ch) {
        if (ch == 0) {
            const float* gw1 = wT + (wv * 16 + 8) * 576;
            #pragma unroll
            for (int i = 0; i < 18; ++i)
                pref[i] = *(const float4*)&gw1[(i * 64 + lane) * 4];
        }
        for (int cl = 0; cl < 8; ++cl) {
            int cib = wv * 16 + ch * 8 + cl;
            float xrow[3][10];
            #pragma unroll
            for (int kh = 0; kh < 3; ++kh) {
                const float* xr = &x_s[cib * 132 + (r + kh) * 12];
                float4 a0 = *(const float4*)&xr[0];
                float4 a1 = *(const float4*)&xr[4];
                float2 a2 = *(const float2*)&xr[8];
                xrow[kh][0] = a0.x; xrow[kh][1] = a0.y; xrow[kh][2] = a0.z; xrow[kh][3] = a0.w;
                xrow[kh][4] = a1.x; xrow[kh][5] = a1.y; xrow[kh][6] = a1.z; xrow[kh][7] = a1.w;
                xrow[kh][8] = a2.x; xrow[kh][9] = a2.y;
            }
            const float* wp = &myw[cl * 576];
            #pragma unroll
            for (int kh = 0; kh < 3; ++kh) {
                #pragma unroll
                for (int kw = 0; kw < 3; ++kw) {
                    const float* wp2 = wp + (kh * 3 + kw) * 64 + (cg << 3);
                    float4 wa = *(const float4*)&wp2[0];
                    float4 wb = *(const float4*)&wp2[4];
                    #pragma unroll
                    for (int j = 0; j < 8; ++j) {
                        float xv = xrow[kh][kw + j];
                        acc[j][0] += xv * wa.x; acc[j][1] += xv * wa.y;
                        acc[j][2] += xv * wa.z; acc[j][3] += xv * wa.w;
                        acc[j][4] += xv * wb.x; acc[j][5] += xv * wb.y;
                        acc[j][6] += xv * wb.z; acc[j][7] += xv * wb.w;
                    }
                }
            }
        }
        if (ch == 0) {
            #pragma unroll
            for (int i = 0; i < 18; ++i)
                *(float4*)&myw[(i * 64 + lane) * 4] = pref[i];
        }
    }

    #pragma unroll
    for (int j = 0; j < 8; ++j) {
        *(float4*)&myw[lane * 68 + (j << 3)]     = make_float4(acc[j][0], acc[j][1], acc[j][2], acc[j][3]);
        *(float4*)&myw[lane * 68 + (j << 3) + 4] = make_float4(acc[j][4], acc[j][5], acc[j][6], acc[j][7]);
    }
    __syncthreads();

    float bv = bias[lane];
    float ssum = 0.f, ssq = 0.f;
    #pragma unroll
    for (int pp = 0; pp < 16; ++pp) {
        int pr = (wv << 1) + (pp >> 3);
        int pc = pp & 7;
        int ol = (pr << 3) + (lane >> 3);
        int ix = (pc << 3) + (lane & 7);
        float s = w_s[ol * 68 + ix] + w_s[4608 + ol * 68 + ix]
                + w_s[9216 + ol * 68 + ix] + w_s[13824 + ol * 68 + ix] + bv;
        out[(((long)((b << 12) + ((ty0 + pr) << 6) + tx0 + pc)) << 6) + lane] = s;
        ssum += s; ssq += s * s;
    }
    float* red = x_s;
    red[(wv << 6) + lane] = ssum;
    red[256 + (wv << 6) + lane] = ssq;
    __syncthreads();
    if (tid < 64) {
        float a = red[tid] + red[64 + tid] + red[128 + tid] + red[192 + tid];
        float q = red[256 + tid] + red[320 + tid] + red[384 + tid] + red[448 + tid];
        atomicAdd(&stats2[tid], a);
        atomicAdd(&stats2[64 + tid], q);
    }
}

// ------- decoder conv2 FUSED with BN+ReLU (inline stats) -------
__global__ void k_dec2_fused(const float* __restrict__ src, const float* __restrict__ stats2,
                             const float* __restrict__ g, const float* __restrict__ be,
                             const float* __restrict__ wT, const float* __restrict__ bias,
                             float* __restrict__ out) {
    __shared__ float x_s[64 * 101];
    __shared__ float w_s[64 * NFC * 12];
    __shared__ float sc_s[64];
    __shared__ float sh_s[64];
    int tile = blockIdx.x;
    int b = blockIdx.y;
    int ty0 = (tile >> 3) << 3;
    int tx0 = (tile & 7) << 3;
    int tid = threadIdx.x;

    if (tid < 64) {
        float m = stats2[tid] * (1.f / 16384.f);
        float var = stats2[64 + tid] * (1.f / 16384.f) - m * m;
        float s = g[tid] * rsqrtf(var + 1e-5f);
        sc_s[tid] = s;
        sh_s[tid] = be[tid] - m * s;
    }
    for (int i = tid; i < 64 * NFC * 12; i += 256)
        w_s[i] = wT[i];
    __syncthreads();

    for (int i = tid; i < 6400; i += 256) {
        int pl = i >> 6;
        int c = i & 63;
        int py = pl / 10, px = pl - py * 10;
        int ih = ty0 + py - 1, iw = tx0 + px - 1;
        float v = 0.f;
        if (ih >= 0 && ih < HH && iw >= 0 && iw < WWD) {
            v = src[((long)((b << 12) + (ih << 6) + iw)) * 64 + c];
            v = fmaxf(v * sc_s[c] + sh_s[c], 0.f);
        }
        x_s[c * 101 + pl] = v;
    }
    __syncthreads();

    int px = tid & 63;
    int py = px >> 3, pxx = px & 7;
    int cog = tid >> 6;
    float acc[3] = {0.f, 0.f, 0.f};
    int nco = (cog < 2) ? 3 : 2;

    for (int ci = 0; ci < 64; ++ci) {
        const float* xr = &x_s[ci * 101 + py * 10 + pxx];
        float xv[9];
        #pragma unroll
        for (int kh = 0; kh < 3; ++kh)
            #pragma unroll
            for (int kw = 0; kw < 3; ++kw)
                xv[kh * 3 + kw] = xr[kh * 10 + kw];
        #pragma unroll
        for (int j = 0; j < 3; ++j) {
            if (j >= nco) break;
            int co = cog + (j << 2);
            const float* wp = &w_s[(ci * NFC + co) * 12];
            float4 w0 = *(const float4*)&wp[0];
            float4 w1 = *(const float4*)&wp[4];
            float  w8 = wp[8];
            acc[j] += xv[0] * w0.x + xv[1] * w0.y + xv[2] * w0.z + xv[3] * w0.w
                    + xv[4] * w1.x + xv[5] * w1.y + xv[6] * w1.z + xv[7] * w1.w
                    + xv[8] * w8;
        }
    }
    int hw = ((ty0 + py) << 6) + tx0 + pxx;
    #pragma unroll
    for (int j = 0; j < 3; ++j) {
        if (j >= nco) break;
        int co = cog + (j << 2);
        out[((long)(b * NFC + co) << 12) + hw] = acc[j] + bias[co];
    }
}

extern "C" void kernel_launch(void* const* d_in, const int* in_sizes, int n_in,
                              void* d_out, int out_size, void* d_ws, size_t ws_size,
                              hipStream_t stream) {
    const float* x       = (const float*)d_in[0];
    const float* enc_w   = (const float*)d_in[1];
    const float* enc_b   = (const float*)d_in[2];
    const float* enc_g   = (const float*)d_in[3];
    const float* enc_be  = (const float*)d_in[4];
    const float* in_proj = (const float*)d_in[5];
    const float* conv_w  = (const float*)d_in[6];
    const float* conv_b  = (const float*)d_in[7];
    const float* x_proj  = (const float*)d_in[8];
    const float* dt_w    = (const float*)d_in[9];
    const float* dt_b    = (const float*)d_in[10];
    const float* A_log   = (const float*)d_in[11];
    const float* Dp      = (const float*)d_in[12];
    const float* out_prj = (const float*)d_in[13];
    const float* dec1_w  = (const float*)d_in[14];
    const float* dec1_b  = (const float*)d_in[15];
    const float* dec1_g  = (const float*)d_in[16];
    const float* dec1_be = (const float*)d_in[17];
    const float* dec2_w  = (const float*)d_in[18];
    const float* dec2_b  = (const float*)d_in[19];
    float* out = (float*)d_out;

    float* ws = (float*)d_ws;
    size_t off = 0;
    float* conv_buf  = ws + off; off += 1048576;  // enc/dec scratch; Pb during layers
    float* stats     = ws + off; off += 128;
    float* stats2    = ws + off; off += 128;
    float* wT1       = ws + off; off += 36864;
    float* wT2       = ws + off; off += 7680;
    float* wTin      = ws + off; off += 65536;
    float* wTout     = ws + off; off += 32768;
    float* t_buf     = ws + off; off += 1048576;
    float* xz_buf    = ws + off; off += 4194304;
    float* xi_buf    = ws + off; off += 2097152;
    float* xdbc_buf  = ws + off; off += 589824;
    float* delta_buf = ws + off; off += 2097152;
    float* gated_buf = ws + off; off += 2097152;  // first 1M floats double as Sb
    (void)ws_size; (void)in_sizes; (void)n_in; (void)out_size;

    float* Pb = conv_buf;
    float* Sb = gated_buf;

    // prep: transposes + zero stats (runs every launch; graph-safe)
    k_prep_all<<<560, 256, 0, stream>>>(in_proj, out_prj, dec1_w, dec2_w,
                                        wTin, wTout, wT1, wT2, stats, stats2);

    // encoder
    k_enc_conv<<<4096, 256, 0, stream>>>(x, enc_w, enc_b, conv_buf, stats);
    k_bn_tr_seq<<<256, 256, 0, stream>>>(conv_buf, stats, enc_g, enc_be, t_buf);

    // mamba layers
    dim3 sg(NCHUNK, BB, 2);
    k_gemm_in2<<<512, 256, 0, stream>>>(t_buf, wTin, xz_buf);
    for (int i = 0; i < NLAYER; ++i) {
        k_xproj_fused<<<512, 256, 0, stream>>>(xz_buf, conv_w + i * DIM * DCN,
                                               conv_b + i * DIM, x_proj + i * 36 * DIM,
                                               dt_w + i * DIM * DTRK, dt_b + i * DIM,
                                               A_log + i * DIM * DSN,
                                               xi_buf, xdbc_buf, delta_buf, Pb, Sb);
        k_scan_p2<<<32, 256, 0, stream>>>(Pb, Sb);
        k_scan_p3<<<sg, 256, 0, stream>>>(delta_buf, xi_buf, xdbc_buf,
                                          A_log + i * DIM * DSN, Dp + i * DIM,
                                          xz_buf, Pb, gated_buf);
        if (i < NLAYER - 1)
            k_gemm_oi<<<512, 256, 0, stream>>>(gated_buf, wTout + i * 8192,
                                               wTin + (i + 1) * 16384, t_buf, xz_buf);
    }
    k_gemm_out2<<<256, 256, 0, stream>>>(gated_buf, wTout + 3 * 8192, t_buf);

    // decoder
    dim3 dg1(64, BB);
    k_dec1_new<<<dg1, 256, 0, stream>>>(t_buf, wT1, dec1_b, conv_buf, stats2);
    k_dec2_fused<<<dg1, 256, 0, stream>>>(conv_buf, stats2, dec1_g, dec1_be, wT2, dec2_b, out);
}

// Round 12
// 509.162 us; speedup vs baseline: 2.4181x; 2.4181x over previous
//
#include <hip/hip_runtime.h>
#include <hip/hip_bf16.h>

// Problem constants (MinimalEventMamba)
#define BB   4
#define NBC  5
#define HD   64
#define NLAYER 4
#define NFC  10
#define DIM  128
#define DSN  16
#define DCN  4
#define DTRK 4
#define HH   64
#define WWD  64
#define LL   4096
#define MM   (BB*LL)
#define NCHUNK 128
#define CLEN   32
#define TSTEP  16

// ---------------- prep: all weight transposes + zero stats ----------------
__global__ void k_prep_all(const float* __restrict__ in_proj, const float* __restrict__ out_proj,
                           const float* __restrict__ dec1_w, const float* __restrict__ dec2_w,
                           float* __restrict__ wTin, float* __restrict__ wTout,
                           float* __restrict__ wT1, float* __restrict__ wT2,
                           float* __restrict__ stats, float* __restrict__ stats2) {
    int idx = blockIdx.x * blockDim.x + threadIdx.x;
    if (idx < 65536) {
        int n = idx & 255, k = (idx >> 8) & 63, l = idx >> 14;
        wTin[idx] = in_proj[(l << 14) + (n << 6) + k];
    } else if (idx < 98304) {
        int j = idx - 65536;
        int n = j & 63, k = (j >> 6) & 127, l = j >> 13;
        wTout[j] = out_proj[(l << 13) + (n << 7) + k];
    } else if (idx < 135168) {
        int j = idx - 98304;
        int co = j & 63, tap = (j >> 6) % 9, ci = j / 576;
        wT1[j] = dec1_w[co * 576 + ci * 9 + tap];
    } else if (idx < 142848) {
        int j = idx - 135168;
        int tap = j % 12, t2 = j / 12, co = t2 % NFC, ci = t2 / NFC;
        wT2[j] = (tap < 9) ? dec2_w[co * 576 + ci * 9 + tap] : 0.f;
    } else if (idx < 143104) {
        int j = idx - 142848;
        if (j < 128) stats[j] = 0.f; else stats2[j - 128] = 0.f;
    }
}

// ---------------- Encoder conv + fused BN-stat partials ----------------
__global__ void k_enc_conv(const float* __restrict__ x, const float* __restrict__ w,
                           const float* __restrict__ bias, float* __restrict__ out,
                           float* __restrict__ stats) {
    __shared__ float r1[256], r2[256];
    int tid = threadIdx.x;
    int idx = blockIdx.x * 256 + tid;
    int wx = idx & 63;
    int hy = (idx >> 6) & 63;
    int co = (idx >> 12) & 63;
    int b  = idx >> 18;
    float acc = bias[co];
    for (int ci = 0; ci < NBC; ++ci) {
        const float* xin = x + (((long)(b * NBC + ci)) << 12);
        const float* wp  = w + (co * NBC + ci) * 9;
        #pragma unroll
        for (int kh = 0; kh < 3; ++kh) {
            int ih = hy + kh - 1;
            if (ih < 0 || ih >= HH) continue;
            #pragma unroll
            for (int kw = 0; kw < 3; ++kw) {
                int iw = wx + kw - 1;
                if (iw < 0 || iw >= WWD) continue;
                acc += xin[(ih << 6) + iw] * wp[kh * 3 + kw];
            }
        }
    }
    out[idx] = acc;
    r1[tid] = acc; r2[tid] = acc * acc;
    __syncthreads();
    for (int off = 128; off > 0; off >>= 1) {
        if (tid < off) { r1[tid] += r1[tid + off]; r2[tid] += r2[tid + off]; }
        __syncthreads();
    }
    if (tid == 0) {
        atomicAdd(&stats[co], r1[0]);
        atomicAdd(&stats[64 + co], r2[0]);
    }
}

// ---- in_proj GEMM (first layer) with FUSED BN+ReLU apply from NCHW conv_buf ----
// m-tile = 64 consecutive pixels of one batch == bn_tr_seq tile. Writes t_buf + xz.
__global__ __launch_bounds__(256, 1) void k_gemm_in_bn(const float* __restrict__ src,
                                                       const float* __restrict__ stats,
                                                       const float* __restrict__ g,
                                                       const float* __restrict__ be,
                                                       const float* __restrict__ wT,
                                                       float* __restrict__ tout,
                                                       float* __restrict__ xz) {
    __shared__ __align__(16) float ts[64 * 68];
    __shared__ float sc[64], sh[64];
    long m0 = (long)blockIdx.x << 6;
    int b = (int)(m0 >> 12);
    int hw0 = (int)(m0 & 4095);
    int tid = threadIdx.x;
    if (tid < 64) {
        float m = stats[tid] * (1.f / 16384.f);
        float var = stats[64 + tid] * (1.f / 16384.f) - m * m;
        float ss = g[tid] * rsqrtf(var + 1e-5f);
        sc[tid] = ss; sh[tid] = be[tid] - m * ss;
    }
    __syncthreads();
    // stage with inline BN+ReLU: coalesced global read over pix; ts[pix][c]
    for (int i = tid; i < 4096; i += 256) {
        int pix = i & 63, c = i >> 6;
        float v = src[(((long)((b << 6) + c)) << 12) + hw0 + pix];
        ts[pix * 68 + c] = fmaxf(v * sc[c] + sh[c], 0.f);
    }
    __syncthreads();
    // write t coalesced (lanes vary c)
    for (int i = tid; i < 4096; i += 256) {
        int r = i >> 6, c = i & 63;
        tout[(m0 + r) * 64 + c] = ts[r * 68 + c];
    }
    // GEMM (identical to r7/r10 k_gemm_in2)
    int rg = tid >> 5;
    int cg = tid & 31;
    float acc[8][8] = {};
    int n0 = cg << 3;
    for (int k4 = 0; k4 < 16; ++k4) {
        float4 a[8];
        #pragma unroll
        for (int r2 = 0; r2 < 8; ++r2)
            a[r2] = *(const float4*)&ts[((rg << 3) + r2) * 68 + (k4 << 2)];
        #pragma unroll
        for (int kk = 0; kk < 4; ++kk) {
            const float* wr = wT + (((k4 << 2) + kk) << 8) + n0;
            float4 w0 = *(const float4*)&wr[0];
            float4 w1 = *(const float4*)&wr[4];
            #pragma unroll
            for (int r2 = 0; r2 < 8; ++r2) {
                float av = (kk == 0) ? a[r2].x : (kk == 1) ? a[r2].y
                         : (kk == 2) ? a[r2].z : a[r2].w;
                acc[r2][0] += av * w0.x; acc[r2][1] += av * w0.y;
                acc[r2][2] += av * w0.z; acc[r2][3] += av * w0.w;
                acc[r2][4] += av * w1.x; acc[r2][5] += av * w1.y;
                acc[r2][6] += av * w1.z; acc[r2][7] += av * w1.w;
            }
        }
    }
    #pragma unroll
    for (int r2 = 0; r2 < 8; ++r2) {
        long m = m0 + (rg << 3) + r2;
        *(float4*)&xz[(m << 8) + n0]     = make_float4(acc[r2][0], acc[r2][1], acc[r2][2], acc[r2][3]);
        *(float4*)&xz[(m << 8) + n0 + 4] = make_float4(acc[r2][4], acc[r2][5], acc[r2][6], acc[r2][7]);
    }
}

// ---------------- fused out_proj(i) + residual + in_proj(i+1): 64-row tiles (r7 optimum) ----------------
__global__ __launch_bounds__(256, 1) void k_gemm_oi(const float* __restrict__ gated,
                                                    const float* __restrict__ wTo,
                                                    const float* __restrict__ wTi,
                                                    float* __restrict__ tio,
                                                    float* __restrict__ xz) {
    __shared__ __align__(16) float g_s[64 * 132];
    __shared__ __align__(16) float t_s[64 * 68];
    long m0 = (long)blockIdx.x << 6;
    int tid = threadIdx.x;
    for (int i = tid; i < 8192; i += 256) {
        int r = i >> 7, k = i & 127;
        g_s[r * 132 + k] = gated[(m0 << 7) + i];
    }
    __syncthreads();
    {
        int rg = tid >> 4, cg = tid & 15;
        int n0 = cg << 2;
        float acc[4][4] = {};
        for (int k4 = 0; k4 < 32; ++k4) {
            float4 a[4];
            #pragma unroll
            for (int r2 = 0; r2 < 4; ++r2)
                a[r2] = *(const float4*)&g_s[((rg << 2) + r2) * 132 + (k4 << 2)];
            #pragma unroll
            for (int kk = 0; kk < 4; ++kk) {
                const float* wr = wTo + (((k4 << 2) + kk) << 6) + n0;
                float4 w0 = *(const float4*)&wr[0];
                #pragma unroll
                for (int r2 = 0; r2 < 4; ++r2) {
                    float av = (kk == 0) ? a[r2].x : (kk == 1) ? a[r2].y
                             : (kk == 2) ? a[r2].z : a[r2].w;
                    acc[r2][0] += av * w0.x; acc[r2][1] += av * w0.y;
                    acc[r2][2] += av * w0.z; acc[r2][3] += av * w0.w;
                }
            }
        }
        #pragma unroll
        for (int r2 = 0; r2 < 4; ++r2) {
            long m = m0 + (rg << 2) + r2;
            float4 t0 = *(const float4*)&tio[(m << 6) + n0];
            t0.x += acc[r2][0]; t0.y += acc[r2][1];
            t0.z += acc[r2][2]; t0.w += acc[r2][3];
            *(float4*)&tio[(m << 6) + n0] = t0;
            *(float4*)&t_s[((rg << 2) + r2) * 68 + n0] = t0;
        }
    }
    __syncthreads();
    {
        int rg = tid >> 5, cg = tid & 31;
        int n0 = cg << 3;
        float acc[8][8] = {};
        for (int k4 = 0; k4 < 16; ++k4) {
            float4 a[8];
            #pragma unroll
            for (int r2 = 0; r2 < 8; ++r2)
                a[r2] = *(const float4*)&t_s[((rg << 3) + r2) * 68 + (k4 << 2)];
            #pragma unroll
            for (int kk = 0; kk < 4; ++kk) {
                const float* wr = wTi + (((k4 << 2) + kk) << 8) + n0;
                float4 w0 = *(const float4*)&wr[0];
                float4 w1 = *(const float4*)&wr[4];
                #pragma unroll
                for (int r2 = 0; r2 < 8; ++r2) {
                    float av = (kk == 0) ? a[r2].x : (kk == 1) ? a[r2].y
                             : (kk == 2) ? a[r2].z : a[r2].w;
                    acc[r2][0] += av * w0.x; acc[r2][1] += av * w0.y;
                    acc[r2][2] += av * w0.z; acc[r2][3] += av * w0.w;
                    acc[r2][4] += av * w1.x; acc[r2][5] += av * w1.y;
                    acc[r2][6] += av * w1.z; acc[r2][7] += av * w1.w;
                }
            }
        }
        #pragma unroll
        for (int r2 = 0; r2 < 8; ++r2) {
            long m = m0 + (rg << 3) + r2;
            *(float4*)&xz[(m << 8) + n0]     = make_float4(acc[r2][0], acc[r2][1], acc[r2][2], acc[r2][3]);
            *(float4*)&xz[(m << 8) + n0 + 4] = make_float4(acc[r2][4], acc[r2][5], acc[r2][6], acc[r2][7]);
        }
    }
}

// ---------------- out_proj GEMM (final layer): 64-row tiles ----------------
__global__ __launch_bounds__(256, 1) void k_gemm_out2(const float* __restrict__ gated,
                                                      const float* __restrict__ wT,
                                                      float* __restrict__ tio) {
    __shared__ __align__(16) float ts[64 * 132];
    long m0 = (long)blockIdx.x << 6;
    int tid = threadIdx.x;
    int rg = tid >> 4;
    int cg = tid & 15;
    for (int i = tid; i < 8192; i += 256) {
        int r2 = i >> 7, k = i & 127;
        ts[r2 * 132 + k] = gated[(m0 << 7) + i];
    }
    __syncthreads();
    float acc[4][4] = {};
    int n0 = cg << 2;
    for (int k4 = 0; k4 < 32; ++k4) {
        float4 a[4];
        #pragma unroll
        for (int r2 = 0; r2 < 4; ++r2)
            a[r2] = *(const float4*)&ts[((rg << 2) + r2) * 132 + (k4 << 2)];
        #pragma unroll
        for (int kk = 0; kk < 4; ++kk) {
            const float* wr = wT + (((k4 << 2) + kk) << 6) + n0;
            float4 w0 = *(const float4*)&wr[0];
            #pragma unroll
            for (int r2 = 0; r2 < 4; ++r2) {
                float av = (kk == 0) ? a[r2].x : (kk == 1) ? a[r2].y
                         : (kk == 2) ? a[r2].z : a[r2].w;
                acc[r2][0] += av * w0.x; acc[r2][1] += av * w0.y;
                acc[r2][2] += av * w0.z; acc[r2][3] += av * w0.w;
            }
        }
    }
    #pragma unroll
    for (int r2 = 0; r2 < 4; ++r2) {
        long m = m0 + (rg << 2) + r2;
        float4 t0 = *(const float4*)&tio[(m << 6) + n0];
        t0.x += acc[r2][0]; t0.y += acc[r2][1];
        t0.z += acc[r2][2]; t0.w += acc[r2][3];
        *(float4*)&tio[(m << 6) + n0] = t0;
    }
}

// ------- x_proj + dwconv+SiLU + dt-softplus + FUSED SCAN PHASE 1 -------
__global__ __launch_bounds__(256, 2) void k_xproj_fused(
        const float* __restrict__ xz, const float* __restrict__ cw,
        const float* __restrict__ cb, const float* __restrict__ Wx,
        const float* __restrict__ dw, const float* __restrict__ dbias,
        const float* __restrict__ A_log,
        float* __restrict__ xi, float* __restrict__ xdbc,
        float* __restrict__ delta, float* __restrict__ Pb, float* __restrict__ Sb) {
    __shared__ float xz_s[35 * 132];     // reused as delta_s after dwconv phase
    __shared__ float xi_s[32 * 132];
    __shared__ float w_s[36 * 132];
    __shared__ float xs[32 * 40];
    __shared__ float cwT[4 * 128];
    __shared__ float cb_s[128];
    long m0 = (long)blockIdx.x << 5;
    int l0 = (int)(m0 & 4095);
    int b = (int)(m0 >> 12);
    int chunk = l0 >> 5;
    int tid = threadIdx.x;

    for (int i = tid; i < 35 * 128; i += 256) {
        int j = i >> 7, k = i & 127;
        int l = l0 - 3 + j;
        float v = 0.f;
        if (l >= 0) v = xz[(m0 - 3 + j) * 256 + k];
        xz_s[j * 132 + k] = v;
    }
    if (tid < 128) cb_s[tid] = cb[tid];
    for (int i = tid; i < 512; i += 256) {
        int kk = i >> 7, di = i & 127;
        cwT[(kk << 7) + di] = cw[(di << 2) + kk];
    }
    for (int i = tid; i < 4608; i += 256) {
        int n = i >> 7, k = i & 127;
        w_s[n * 132 + k] = Wx[i];
    }
    __syncthreads();

    for (int ii = 0; ii < 4; ++ii) {
        int i = tid + (ii << 8);
        int r = i >> 5;
        int d4 = (i & 31) << 2;
        float4 a = *(const float4*)&cb_s[d4];
        #pragma unroll
        for (int kk = 0; kk < 4; ++kk) {
            float4 xv = *(const float4*)&xz_s[(r + kk) * 132 + d4];
            float4 wv = *(const float4*)&cwT[(kk << 7) + d4];
            a.x += xv.x * wv.x; a.y += xv.y * wv.y;
            a.z += xv.z * wv.z; a.w += xv.w * wv.w;
        }
        a.x = a.x / (1.f + __expf(-a.x));
        a.y = a.y / (1.f + __expf(-a.y));
        a.z = a.z / (1.f + __expf(-a.z));
        a.w = a.w / (1.f + __expf(-a.w));
        *(float4*)&xi_s[r * 132 + d4] = a;
        *(float4*)&xi[(m0 + r) * 128 + d4] = a;
    }
    __syncthreads();

    int n = tid & 63;
    int rg = tid >> 6;
    if (n < 36) {
        float acc[8] = {0,0,0,0,0,0,0,0};
        for (int k4 = 0; k4 < 32; ++k4) {
            float4 w4 = *(const float4*)&w_s[n * 132 + (k4 << 2)];
            #pragma unroll
            for (int r = 0; r < 8; ++r) {
                float4 a4 = *(const float4*)&xi_s[((rg << 3) + r) * 132 + (k4 << 2)];
                acc[r] += a4.x * w4.x + a4.y * w4.y + a4.z * w4.z + a4.w * w4.w;
            }
        }
        #pragma unroll
        for (int r = 0; r < 8; ++r) {
            int rr = (rg << 3) + r;
            xdbc[(m0 + rr) * 36 + n] = acc[r];
            xs[rr * 40 + n] = acc[r];
        }
    }
    __syncthreads();

    float* delta_s = xz_s;
    for (int i = tid; i < 4096; i += 256) {
        int r = i >> 7, di = i & 127;
        float v = dbias[di];
        float4 d4 = *(const float4*)&dw[di << 2];
        v += xs[r * 40 + 0] * d4.x + xs[r * 40 + 1] * d4.y
           + xs[r * 40 + 2] * d4.z + xs[r * 40 + 3] * d4.w;
        float sp = (v > 20.f) ? v : log1pf(expf(v));
        delta[(m0 + r) * 128 + di] = sp;
        delta_s[r * 132 + di] = sp;
    }
    __syncthreads();

    {
        int di = tid >> 1;
        int dso = (tid & 1) << 3;
        float4 al0 = *(const float4*)&A_log[(di << 4) + dso];
        float4 al1 = *(const float4*)&A_log[(di << 4) + dso + 4];
        float Av[8] = { -expf(al0.x), -expf(al0.y), -expf(al0.z), -expf(al0.w),
                        -expf(al1.x), -expf(al1.y), -expf(al1.z), -expf(al1.w) };
        float h[8] = {0,0,0,0,0,0,0,0};
        float P[8] = {1,1,1,1,1,1,1,1};
        #pragma unroll 4
        for (int i = 0; i < CLEN; ++i) {
            float d = delta_s[i * 132 + di];
            float u = xi_s[i * 132 + di];
            float du = d * u;
            float4 B0 = *(float4*)&xs[i * 40 + DTRK + dso];
            float4 B1 = *(float4*)&xs[i * 40 + DTRK + dso + 4];
            float a0 = __expf(d * Av[0]); h[0] = a0 * h[0] + du * B0.x; P[0] *= a0;
            float a1 = __expf(d * Av[1]); h[1] = a1 * h[1] + du * B0.y; P[1] *= a1;
            float a2 = __expf(d * Av[2]); h[2] = a2 * h[2] + du * B0.z; P[2] *= a2;
            float a3 = __expf(d * Av[3]); h[3] = a3 * h[3] + du * B0.w; P[3] *= a3;
            float a4 = __expf(d * Av[4]); h[4] = a4 * h[4] + du * B1.x; P[4] *= a4;
            float a5 = __expf(d * Av[5]); h[5] = a5 * h[5] + du * B1.y; P[5] *= a5;
            float a6 = __expf(d * Av[6]); h[6] = a6 * h[6] + du * B1.z; P[6] *= a6;
            float a7 = __expf(d * Av[7]); h[7] = a7 * h[7] + du * B1.w; P[7] *= a7;
        }
        long o = (((long)chunk * BB + b) << 11) + (di << 4) + dso;
        *(float4*)&Pb[o]     = make_float4(P[0], P[1], P[2], P[3]);
        *(float4*)&Pb[o + 4] = make_float4(P[4], P[5], P[6], P[7]);
        *(float4*)&Sb[o]     = make_float4(h[0], h[1], h[2], h[3]);
        *(float4*)&Sb[o + 4] = make_float4(h[4], h[5], h[6], h[7]);
    }
}

// ---------------- scan phase 2 (stitch) and phase 3 (replay+gate) ----------------
__global__ void k_scan_p2(float* Pb, const float* __restrict__ Sb) {
    int t = blockIdx.x * blockDim.x + threadIdx.x;
    int b = t >> 11;
    int s = t & 2047;
    float h = 0.f;
    for (int c = 0; c < NCHUNK; ++c) {
        long idx = (((long)c * BB + b) << 11) + s;
        float p = Pb[idx];
        float sv = Sb[idx];
        Pb[idx] = h;
        h = p * h + sv;
    }
}

__global__ void k_scan_p3(const float* __restrict__ delta, const float* __restrict__ xi,
                          const float* __restrict__ xdbc, const float* __restrict__ A_log,
                          const float* __restrict__ Dp, const float* __restrict__ xz,
                          const float* __restrict__ hin, float* __restrict__ gated) {
    __shared__ float d_s[TSTEP][64];
    __shared__ float u_s[TSTEP][64];
    __shared__ float bc_s[TSTEP][32];
    __shared__ float y_s[TSTEP][64];
    int chunk = blockIdx.x, b = blockIdx.y, half = blockIdx.z;
    int tid = threadIdx.x;
    int dq = tid & 3;
    int dil = tid >> 2;
    int di = (half << 6) + dil;
    float4 al = *(const float4*)&A_log[(di << 4) + (dq << 2)];
    float Av[4] = { -expf(al.x), -expf(al.y), -expf(al.z), -expf(al.w) };
    float Dv = Dp[di];
    long ho = (((long)chunk * BB + b) << 11) + (di << 4) + (dq << 2);
    float4 h4 = *(const float4*)&hin[ho];
    float h[4] = { h4.x, h4.y, h4.z, h4.w };
    long t0 = ((long)b << 12) + (long)chunk * CLEN;

    int srow = tid >> 4, sc4 = (tid & 15) << 2;
    for (int tile = 0; tile < CLEN / TSTEP; ++tile) {
        __syncthreads();
        long ls = t0 + tile * TSTEP + srow;
        *(float4*)&d_s[srow][sc4] = *(const float4*)&delta[(ls << 7) + (half << 6) + sc4];
        *(float4*)&u_s[srow][sc4] = *(const float4*)&xi[(ls << 7) + (half << 6) + sc4];
        if (tid < 128) {
            int r2 = tid >> 3, cc = (tid & 7) << 2;
            long l2 = t0 + tile * TSTEP + r2;
            *(float4*)&bc_s[r2][cc] = *(const float4*)&xdbc[l2 * 36 + DTRK + cc];
        }
        __syncthreads();
        #pragma unroll
        for (int i = 0; i < TSTEP; ++i) {
            float d = d_s[i][dil];
            float u = u_s[i][dil];
            float du = d * u;
            float4 Bv = *(float4*)&bc_s[i][dq << 2];
            float4 Cv = *(float4*)&bc_s[i][16 + (dq << 2)];
            float a0 = __expf(d * Av[0]); h[0] = a0 * h[0] + du * Bv.x;
            float a1 = __expf(d * Av[1]); h[1] = a1 * h[1] + du * Bv.y;
            float a2 = __expf(d * Av[2]); h[2] = a2 * h[2] + du * Bv.z;
            float a3 = __expf(d * Av[3]); h[3] = a3 * h[3] + du * Bv.w;
            float yp = h[0] * Cv.x + h[1] * Cv.y + h[2] * Cv.z + h[3] * Cv.w;
            yp += __shfl_xor(yp, 1);
            yp += __shfl_xor(yp, 2);
            if (dq == 0)
                y_s[i][dil] = yp + u * Dv;
        }
        __syncthreads();
        {
            long l = t0 + tile * TSTEP + srow;
            float4 y4 = *(float4*)&y_s[srow][sc4];
            float4 z4 = *(const float4*)&xz[(l << 8) + DIM + (half << 6) + sc4];
            float4 og;
            og.x = y4.x * (z4.x / (1.f + __expf(-z4.x)));
            og.y = y4.y * (z4.y / (1.f + __expf(-z4.y)));
            og.z = y4.z * (z4.z / (1.f + __expf(-z4.z)));
            og.w = y4.w * (z4.w / (1.f + __expf(-z4.w)));
            *(float4*)&gated[(l << 7) + (half << 6) + sc4] = og;
        }
    }
}

// ---------------- decoder conv1 + fused BN-stat partials ----------------
__global__ __launch_bounds__(256, 1) void k_dec1_new(const float* __restrict__ tin,
                                                     const float* __restrict__ wT,
                                                     const float* __restrict__ bias,
                                                     float* __restrict__ out,
                                                     float* __restrict__ stats2) {
    __shared__ __align__(16) float x_s[64 * 132];
    __shared__ __align__(16) float w_s[4 * 4608];
    int tile = blockIdx.x;
    int b = blockIdx.y;
    int ty0 = (tile >> 3) << 3;
    int tx0 = (tile & 7) << 3;
    int tid = threadIdx.x;
    int wv = tid >> 6;
    int lane = tid & 63;
    int r = lane >> 3;
    int cg = lane & 7;

    for (int i = tid; i < 6400; i += 256) {
        int pl = i >> 6;
        int c = i & 63;
        int py = pl / 10, px = pl - py * 10;
        int ih = ty0 + py - 1, iw = tx0 + px - 1;
        float v = 0.f;
        if (ih >= 0 && ih < HH && iw >= 0 && iw < WWD)
            v = tin[(((long)((b << 12) + (ih << 6) + iw)) << 6) + c];
        x_s[c * 132 + py * 12 + px] = v;
    }
    float* myw = &w_s[wv * 4608];
    const float* gw = wT + (wv * 16) * 576;
    float4 pref[18];
    #pragma unroll
    for (int i = 0; i < 18; ++i)
        pref[i] = *(const float4*)&gw[(i * 64 + lane) * 4];
    #pragma unroll
    for (int i = 0; i < 18; ++i)
        *(float4*)&myw[(i * 64 + lane) * 4] = pref[i];
    __syncthreads();

    float acc[8][8] = {};
    #pragma unroll
    for (int ch = 0; ch < 2; ++ch) {
        if (ch == 0) {
            const float* gw1 = wT + (wv * 16 + 8) * 576;
            #pragma unroll
            for (int i = 0; i < 18; ++i)
                pref[i] = *(const float4*)&gw1[(i * 64 + lane) * 4];
        }
        for (int cl = 0; cl < 8; ++cl) {
            int cib = wv * 16 + ch * 8 + cl;
            float xrow[3][10];
            #pragma unroll
            for (int kh = 0; kh < 3; ++kh) {
                const float* xr = &x_s[cib * 132 + (r + kh) * 12];
                float4 a0 = *(const float4*)&xr[0];
                float4 a1 = *(const float4*)&xr[4];
                float2 a2 = *(const float2*)&xr[8];
                xrow[kh][0] = a0.x; xrow[kh][1] = a0.y; xrow[kh][2] = a0.z; xrow[kh][3] = a0.w;
                xrow[kh][4] = a1.x; xrow[kh][5] = a1.y; xrow[kh][6] = a1.z; xrow[kh][7] = a1.w;
                xrow[kh][8] = a2.x; xrow[kh][9] = a2.y;
            }
            const float* wp = &myw[cl * 576];
            #pragma unroll
            for (int kh = 0; kh < 3; ++kh) {
                #pragma unroll
                for (int kw = 0; kw < 3; ++kw) {
                    const float* wp2 = wp + (kh * 3 + kw) * 64 + (cg << 3);
                    float4 wa = *(const float4*)&wp2[0];
                    float4 wb = *(const float4*)&wp2[4];
                    #pragma unroll
                    for (int j = 0; j < 8; ++j) {
                        float xv = xrow[kh][kw + j];
                        acc[j][0] += xv * wa.x; acc[j][1] += xv * wa.y;
                        acc[j][2] += xv * wa.z; acc[j][3] += xv * wa.w;
                        acc[j][4] += xv * wb.x; acc[j][5] += xv * wb.y;
                        acc[j][6] += xv * wb.z; acc[j][7] += xv * wb.w;
                    }
                }
            }
        }
        if (ch == 0) {
            #pragma unroll
            for (int i = 0; i < 18; ++i)
                *(float4*)&myw[(i * 64 + lane) * 4] = pref[i];
        }
    }

    #pragma unroll
    for (int j = 0; j < 8; ++j) {
        *(float4*)&myw[lane * 68 + (j << 3)]     = make_float4(acc[j][0], acc[j][1], acc[j][2], acc[j][3]);
        *(float4*)&myw[lane * 68 + (j << 3) + 4] = make_float4(acc[j][4], acc[j][5], acc[j][6], acc[j][7]);
    }
    __syncthreads();

    float bv = bias[lane];
    float ssum = 0.f, ssq = 0.f;
    #pragma unroll
    for (int pp = 0; pp < 16; ++pp) {
        int pr = (wv << 1) + (pp >> 3);
        int pc = pp & 7;
        int ol = (pr << 3) + (lane >> 3);
        int ix = (pc << 3) + (lane & 7);
        float s = w_s[ol * 68 + ix] + w_s[4608 + ol * 68 + ix]
                + w_s[9216 + ol * 68 + ix] + w_s[13824 + ol * 68 + ix] + bv;
        out[(((long)((b << 12) + ((ty0 + pr) << 6) + tx0 + pc)) << 6) + lane] = s;
        ssum += s; ssq += s * s;
    }
    float* red = x_s;
    red[(wv << 6) + lane] = ssum;
    red[256 + (wv << 6) + lane] = ssq;
    __syncthreads();
    if (tid < 64) {
        float a = red[tid] + red[64 + tid] + red[128 + tid] + red[192 + tid];
        float q = red[256 + tid] + red[320 + tid] + red[384 + tid] + red[448 + tid];
        atomicAdd(&stats2[tid], a);
        atomicAdd(&stats2[64 + tid], q);
    }
}

// ------- decoder conv2 FUSED with BN+ReLU (inline stats) -------
__global__ void k_dec2_fused(const float* __restrict__ src, const float* __restrict__ stats2,
                             const float* __restrict__ g, const float* __restrict__ be,
                             const float* __restrict__ wT, const float* __restrict__ bias,
                             float* __restrict__ out) {
    __shared__ float x_s[64 * 101];
    __shared__ float w_s[64 * NFC * 12];
    __shared__ float sc_s[64];
    __shared__ float sh_s[64];
    int tile = blockIdx.x;
    int b = blockIdx.y;
    int ty0 = (tile >> 3) << 3;
    int tx0 = (tile & 7) << 3;
    int tid = threadIdx.x;

    if (tid < 64) {
        float m = stats2[tid] * (1.f / 16384.f);
        float var = stats2[64 + tid] * (1.f / 16384.f) - m * m;
        float s = g[tid] * rsqrtf(var + 1e-5f);
        sc_s[tid] = s;
        sh_s[tid] = be[tid] - m * s;
    }
    for (int i = tid; i < 64 * NFC * 12; i += 256)
        w_s[i] = wT[i];
    __syncthreads();

    for (int i = tid; i < 6400; i += 256) {
        int pl = i >> 6;
        int c = i & 63;
        int py = pl / 10, px = pl - py * 10;
        int ih = ty0 + py - 1, iw = tx0 + px - 1;
        float v = 0.f;
        if (ih >= 0 && ih < HH && iw >= 0 && iw < WWD) {
            v = src[((long)((b << 12) + (ih << 6) + iw)) * 64 + c];
            v = fmaxf(v * sc_s[c] + sh_s[c], 0.f);
        }
        x_s[c * 101 + pl] = v;
    }
    __syncthreads();

    int px = tid & 63;
    int py = px >> 3, pxx = px & 7;
    int cog = tid >> 6;
    float acc[3] = {0.f, 0.f, 0.f};
    int nco = (cog < 2) ? 3 : 2;

    for (int ci = 0; ci < 64; ++ci) {
        const float* xr = &x_s[ci * 101 + py * 10 + pxx];
        float xv[9];
        #pragma unroll
        for (int kh = 0; kh < 3; ++kh)
            #pragma unroll
            for (int kw = 0; kw < 3; ++kw)
                xv[kh * 3 + kw] = xr[kh * 10 + kw];
        #pragma unroll
        for (int j = 0; j < 3; ++j) {
            if (j >= nco) break;
            int co = cog + (j << 2);
            const float* wp = &w_s[(ci * NFC + co) * 12];
            float4 w0 = *(const float4*)&wp[0];
            float4 w1 = *(const float4*)&wp[4];
            float  w8 = wp[8];
            acc[j] += xv[0] * w0.x + xv[1] * w0.y + xv[2] * w0.z + xv[3] * w0.w
                    + xv[4] * w1.x + xv[5] * w1.y + xv[6] * w1.z + xv[7] * w1.w
                    + xv[8] * w8;
        }
    }
    int hw = ((ty0 + py) << 6) + tx0 + pxx;
    #pragma unroll
    for (int j = 0; j < 3; ++j) {
        if (j >= nco) break;
        int co = cog + (j << 2);
        out[((long)(b * NFC + co) << 12) + hw] = acc[j] + bias[co];
    }
}

extern "C" void kernel_launch(void* const* d_in, const int* in_sizes, int n_in,
                              void* d_out, int out_size, void* d_ws, size_t ws_size,
                              hipStream_t stream) {
    const float* x       = (const float*)d_in[0];
    const float* enc_w   = (const float*)d_in[1];
    const float* enc_b   = (const float*)d_in[2];
    const float* enc_g   = (const float*)d_in[3];
    const float* enc_be  = (const float*)d_in[4];
    const float* in_proj = (const float*)d_in[5];
    const float* conv_w  = (const float*)d_in[6];
    const float* conv_b  = (const float*)d_in[7];
    const float* x_proj  = (const float*)d_in[8];
    const float* dt_w    = (const float*)d_in[9];
    const float* dt_b    = (const float*)d_in[10];
    const float* A_log   = (const float*)d_in[11];
    const float* Dp      = (const float*)d_in[12];
    const float* out_prj = (const float*)d_in[13];
    const float* dec1_w  = (const float*)d_in[14];
    const float* dec1_b  = (const float*)d_in[15];
    const float* dec1_g  = (const float*)d_in[16];
    const float* dec1_be = (const float*)d_in[17];
    const float* dec2_w  = (const float*)d_in[18];
    const float* dec2_b  = (const float*)d_in[19];
    float* out = (float*)d_out;

    float* ws = (float*)d_ws;
    size_t off = 0;
    float* conv_buf  = ws + off; off += 1048576;  // enc/dec scratch; Pb during layers
    float* stats     = ws + off; off += 128;
    float* stats2    = ws + off; off += 128;
    float* wT1       = ws + off; off += 36864;
    float* wT2       = ws + off; off += 7680;
    float* wTin      = ws + off; off += 65536;
    float* wTout     = ws + off; off += 32768;
    float* t_buf     = ws + off; off += 1048576;
    float* xz_buf    = ws + off; off += 4194304;
    float* xi_buf    = ws + off; off += 2097152;
    float* xdbc_buf  = ws + off; off += 589824;
    float* delta_buf = ws + off; off += 2097152;
    float* gated_buf = ws + off; off += 2097152;  // first 1M floats double as Sb
    (void)ws_size; (void)in_sizes; (void)n_in; (void)out_size;

    float* Pb = conv_buf;
    float* Sb = gated_buf;

    // prep: transposes + zero stats (runs every launch; graph-safe)
    k_prep_all<<<560, 256, 0, stream>>>(in_proj, out_prj, dec1_w, dec2_w,
                                        wTin, wTout, wT1, wT2, stats, stats2);

    // encoder (BN-apply fused into first in_proj)
    k_enc_conv<<<4096, 256, 0, stream>>>(x, enc_w, enc_b, conv_buf, stats);

    // mamba layers
    dim3 sg(NCHUNK, BB, 2);
    k_gemm_in_bn<<<256, 256, 0, stream>>>(conv_buf, stats, enc_g, enc_be, wTin, t_buf, xz_buf);
    for (int i = 0; i < NLAYER; ++i) {
        k_xproj_fused<<<512, 256, 0, stream>>>(xz_buf, conv_w + i * DIM * DCN,
                                               conv_b + i * DIM, x_proj + i * 36 * DIM,
                                               dt_w + i * DIM * DTRK, dt_b + i * DIM,
                                               A_log + i * DIM * DSN,
                                               xi_buf, xdbc_buf, delta_buf, Pb, Sb);
        k_scan_p2<<<32, 256, 0, stream>>>(Pb, Sb);
        k_scan_p3<<<sg, 256, 0, stream>>>(delta_buf, xi_buf, xdbc_buf,
                                          A_log + i * DIM * DSN, Dp + i * DIM,
                                          xz_buf, Pb, gated_buf);
        if (i < NLAYER - 1)
            k_gemm_oi<<<256, 256, 0, stream>>>(gated_buf, wTout + i * 8192,
                                               wTin + (i + 1) * 16384, t_buf, xz_buf);
    }
    k_gemm_out2<<<256, 256, 0, stream>>>(gated_buf, wTout + 3 * 8192, t_buf);

    // decoder
    dim3 dg1(64, BB);
    k_dec1_new<<<dg1, 256, 0, stream>>>(t_buf, wT1, dec1_b, conv_buf, stats2);
    k_dec2_fused<<<dg1, 256, 0, stream>>>(conv_buf, stats2, dec1_g, dec1_be, wT2, dec2_b, out);
}

// Round 13
// 489.800 us; speedup vs baseline: 2.5137x; 1.0395x over previous
//
#include <hip/hip_runtime.h>
#include <hip/hip_bf16.h>

// Problem constants (MinimalEventMamba)
#define BB   4
#define NBC  5
#define HD   64
#define NLAYER 4
#define NFC  10
#define DIM  128
#define DSN  16
#define DCN  4
#define DTRK 4
#define HH   64
#define WWD  64
#define LL   4096
#define MM   (BB*LL)
#define NCHUNK 128
#define CLEN   32
#define TSTEP  16

// ---------------- prep: all weight transposes + zero stats ----------------
__global__ void k_prep_all(const float* __restrict__ in_proj, const float* __restrict__ out_proj,
                           const float* __restrict__ dec1_w, const float* __restrict__ dec2_w,
                           float* __restrict__ wTin, float* __restrict__ wTout,
                           float* __restrict__ wT1, float* __restrict__ wT2,
                           float* __restrict__ stats, float* __restrict__ stats2) {
    int idx = blockIdx.x * blockDim.x + threadIdx.x;
    if (idx < 65536) {
        int n = idx & 255, k = (idx >> 8) & 63, l = idx >> 14;
        wTin[idx] = in_proj[(l << 14) + (n << 6) + k];
    } else if (idx < 98304) {
        int j = idx - 65536;
        int n = j & 63, k = (j >> 6) & 127, l = j >> 13;
        wTout[j] = out_proj[(l << 13) + (n << 7) + k];
    } else if (idx < 135168) {
        int j = idx - 98304;
        int co = j & 63, tap = (j >> 6) % 9, ci = j / 576;
        wT1[j] = dec1_w[co * 576 + ci * 9 + tap];
    } else if (idx < 142848) {
        int j = idx - 135168;
        int tap = j % 12, t2 = j / 12, co = t2 % NFC, ci = t2 / NFC;
        wT2[j] = (tap < 9) ? dec2_w[co * 576 + ci * 9 + tap] : 0.f;
    } else if (idx < 143104) {
        int j = idx - 142848;
        if (j < 128) stats[j] = 0.f; else stats2[j - 128] = 0.f;
    }
}

// ---------------- Encoder conv + fused BN-stat partials ----------------
__global__ void k_enc_conv(const float* __restrict__ x, const float* __restrict__ w,
                           const float* __restrict__ bias, float* __restrict__ out,
                           float* __restrict__ stats) {
    __shared__ float r1[256], r2[256];
    int tid = threadIdx.x;
    int idx = blockIdx.x * 256 + tid;
    int wx = idx & 63;
    int hy = (idx >> 6) & 63;
    int co = (idx >> 12) & 63;
    int b  = idx >> 18;
    float acc = bias[co];
    for (int ci = 0; ci < NBC; ++ci) {
        const float* xin = x + (((long)(b * NBC + ci)) << 12);
        const float* wp  = w + (co * NBC + ci) * 9;
        #pragma unroll
        for (int kh = 0; kh < 3; ++kh) {
            int ih = hy + kh - 1;
            if (ih < 0 || ih >= HH) continue;
            #pragma unroll
            for (int kw = 0; kw < 3; ++kw) {
                int iw = wx + kw - 1;
                if (iw < 0 || iw >= WWD) continue;
                acc += xin[(ih << 6) + iw] * wp[kh * 3 + kw];
            }
        }
    }
    out[idx] = acc;
    r1[tid] = acc; r2[tid] = acc * acc;
    __syncthreads();
    for (int off = 128; off > 0; off >>= 1) {
        if (tid < off) { r1[tid] += r1[tid + off]; r2[tid] += r2[tid + off]; }
        __syncthreads();
    }
    if (tid == 0) {
        atomicAdd(&stats[co], r1[0]);
        atomicAdd(&stats[64 + co], r2[0]);
    }
}

// ---- in_proj GEMM (first layer) with FUSED BN+ReLU apply from NCHW conv_buf ----
__global__ __launch_bounds__(256, 1) void k_gemm_in_bn(const float* __restrict__ src,
                                                       const float* __restrict__ stats,
                                                       const float* __restrict__ g,
                                                       const float* __restrict__ be,
                                                       const float* __restrict__ wT,
                                                       float* __restrict__ tout,
                                                       float* __restrict__ xz) {
    __shared__ __align__(16) float ts[64 * 68];
    __shared__ float sc[64], sh[64];
    long m0 = (long)blockIdx.x << 6;
    int b = (int)(m0 >> 12);
    int hw0 = (int)(m0 & 4095);
    int tid = threadIdx.x;
    if (tid < 64) {
        float m = stats[tid] * (1.f / 16384.f);
        float var = stats[64 + tid] * (1.f / 16384.f) - m * m;
        float ss = g[tid] * rsqrtf(var + 1e-5f);
        sc[tid] = ss; sh[tid] = be[tid] - m * ss;
    }
    __syncthreads();
    for (int i = tid; i < 4096; i += 256) {
        int pix = i & 63, c = i >> 6;
        float v = src[(((long)((b << 6) + c)) << 12) + hw0 + pix];
        ts[pix * 68 + c] = fmaxf(v * sc[c] + sh[c], 0.f);
    }
    __syncthreads();
    for (int i = tid; i < 4096; i += 256) {
        int r = i >> 6, c = i & 63;
        tout[(m0 + r) * 64 + c] = ts[r * 68 + c];
    }
    int rg = tid >> 5;
    int cg = tid & 31;
    float acc[8][8] = {};
    int n0 = cg << 3;
    for (int k4 = 0; k4 < 16; ++k4) {
        float4 a[8];
        #pragma unroll
        for (int r2 = 0; r2 < 8; ++r2)
            a[r2] = *(const float4*)&ts[((rg << 3) + r2) * 68 + (k4 << 2)];
        #pragma unroll
        for (int kk = 0; kk < 4; ++kk) {
            const float* wr = wT + (((k4 << 2) + kk) << 8) + n0;
            float4 w0 = *(const float4*)&wr[0];
            float4 w1 = *(const float4*)&wr[4];
            #pragma unroll
            for (int r2 = 0; r2 < 8; ++r2) {
                float av = (kk == 0) ? a[r2].x : (kk == 1) ? a[r2].y
                         : (kk == 2) ? a[r2].z : a[r2].w;
                acc[r2][0] += av * w0.x; acc[r2][1] += av * w0.y;
                acc[r2][2] += av * w0.z; acc[r2][3] += av * w0.w;
                acc[r2][4] += av * w1.x; acc[r2][5] += av * w1.y;
                acc[r2][6] += av * w1.z; acc[r2][7] += av * w1.w;
            }
        }
    }
    #pragma unroll
    for (int r2 = 0; r2 < 8; ++r2) {
        long m = m0 + (rg << 3) + r2;
        *(float4*)&xz[(m << 8) + n0]     = make_float4(acc[r2][0], acc[r2][1], acc[r2][2], acc[r2][3]);
        *(float4*)&xz[(m << 8) + n0 + 4] = make_float4(acc[r2][4], acc[r2][5], acc[r2][6], acc[r2][7]);
    }
}

// ------- x_proj + dwconv+SiLU + dt-softplus + FUSED SCAN PHASE 1 -------
__global__ __launch_bounds__(256, 2) void k_xproj_fused(
        const float* __restrict__ xz, const float* __restrict__ cw,
        const float* __restrict__ cb, const float* __restrict__ Wx,
        const float* __restrict__ dw, const float* __restrict__ dbias,
        const float* __restrict__ A_log,
        float* __restrict__ xi, float* __restrict__ xdbc,
        float* __restrict__ delta, float* __restrict__ Pb, float* __restrict__ Sb) {
    __shared__ float xz_s[35 * 132];     // reused as delta_s after dwconv phase
    __shared__ float xi_s[32 * 132];
    __shared__ float w_s[36 * 132];
    __shared__ float xs[32 * 40];
    __shared__ float cwT[4 * 128];
    __shared__ float cb_s[128];
    long m0 = (long)blockIdx.x << 5;
    int l0 = (int)(m0 & 4095);
    int b = (int)(m0 >> 12);
    int chunk = l0 >> 5;
    int tid = threadIdx.x;

    for (int i = tid; i < 35 * 128; i += 256) {
        int j = i >> 7, k = i & 127;
        int l = l0 - 3 + j;
        float v = 0.f;
        if (l >= 0) v = xz[(m0 - 3 + j) * 256 + k];
        xz_s[j * 132 + k] = v;
    }
    if (tid < 128) cb_s[tid] = cb[tid];
    for (int i = tid; i < 512; i += 256) {
        int kk = i >> 7, di = i & 127;
        cwT[(kk << 7) + di] = cw[(di << 2) + kk];
    }
    for (int i = tid; i < 4608; i += 256) {
        int n = i >> 7, k = i & 127;
        w_s[n * 132 + k] = Wx[i];
    }
    __syncthreads();

    for (int ii = 0; ii < 4; ++ii) {
        int i = tid + (ii << 8);
        int r = i >> 5;
        int d4 = (i & 31) << 2;
        float4 a = *(const float4*)&cb_s[d4];
        #pragma unroll
        for (int kk = 0; kk < 4; ++kk) {
            float4 xv = *(const float4*)&xz_s[(r + kk) * 132 + d4];
            float4 wv = *(const float4*)&cwT[(kk << 7) + d4];
            a.x += xv.x * wv.x; a.y += xv.y * wv.y;
            a.z += xv.z * wv.z; a.w += xv.w * wv.w;
        }
        a.x = a.x / (1.f + __expf(-a.x));
        a.y = a.y / (1.f + __expf(-a.y));
        a.z = a.z / (1.f + __expf(-a.z));
        a.w = a.w / (1.f + __expf(-a.w));
        *(float4*)&xi_s[r * 132 + d4] = a;
        *(float4*)&xi[(m0 + r) * 128 + d4] = a;
    }
    __syncthreads();

    int n = tid & 63;
    int rg = tid >> 6;
    if (n < 36) {
        float acc[8] = {0,0,0,0,0,0,0,0};
        for (int k4 = 0; k4 < 32; ++k4) {
            float4 w4 = *(const float4*)&w_s[n * 132 + (k4 << 2)];
            #pragma unroll
            for (int r = 0; r < 8; ++r) {
                float4 a4 = *(const float4*)&xi_s[((rg << 3) + r) * 132 + (k4 << 2)];
                acc[r] += a4.x * w4.x + a4.y * w4.y + a4.z * w4.z + a4.w * w4.w;
            }
        }
        #pragma unroll
        for (int r = 0; r < 8; ++r) {
            int rr = (rg << 3) + r;
            xdbc[(m0 + rr) * 36 + n] = acc[r];
            xs[rr * 40 + n] = acc[r];
        }
    }
    __syncthreads();

    float* delta_s = xz_s;
    for (int i = tid; i < 4096; i += 256) {
        int r = i >> 7, di = i & 127;
        float v = dbias[di];
        float4 d4 = *(const float4*)&dw[di << 2];
        v += xs[r * 40 + 0] * d4.x + xs[r * 40 + 1] * d4.y
           + xs[r * 40 + 2] * d4.z + xs[r * 40 + 3] * d4.w;
        float sp = (v > 20.f) ? v : log1pf(expf(v));
        delta[(m0 + r) * 128 + di] = sp;
        delta_s[r * 132 + di] = sp;
    }
    __syncthreads();

    {
        int di = tid >> 1;
        int dso = (tid & 1) << 3;
        float4 al0 = *(const float4*)&A_log[(di << 4) + dso];
        float4 al1 = *(const float4*)&A_log[(di << 4) + dso + 4];
        float Av[8] = { -expf(al0.x), -expf(al0.y), -expf(al0.z), -expf(al0.w),
                        -expf(al1.x), -expf(al1.y), -expf(al1.z), -expf(al1.w) };
        float h[8] = {0,0,0,0,0,0,0,0};
        float P[8] = {1,1,1,1,1,1,1,1};
        #pragma unroll 4
        for (int i = 0; i < CLEN; ++i) {
            float d = delta_s[i * 132 + di];
            float u = xi_s[i * 132 + di];
            float du = d * u;
            float4 B0 = *(float4*)&xs[i * 40 + DTRK + dso];
            float4 B1 = *(float4*)&xs[i * 40 + DTRK + dso + 4];
            float a0 = __expf(d * Av[0]); h[0] = a0 * h[0] + du * B0.x; P[0] *= a0;
            float a1 = __expf(d * Av[1]); h[1] = a1 * h[1] + du * B0.y; P[1] *= a1;
            float a2 = __expf(d * Av[2]); h[2] = a2 * h[2] + du * B0.z; P[2] *= a2;
            float a3 = __expf(d * Av[3]); h[3] = a3 * h[3] + du * B0.w; P[3] *= a3;
            float a4 = __expf(d * Av[4]); h[4] = a4 * h[4] + du * B1.x; P[4] *= a4;
            float a5 = __expf(d * Av[5]); h[5] = a5 * h[5] + du * B1.y; P[5] *= a5;
            float a6 = __expf(d * Av[6]); h[6] = a6 * h[6] + du * B1.z; P[6] *= a6;
            float a7 = __expf(d * Av[7]); h[7] = a7 * h[7] + du * B1.w; P[7] *= a7;
        }
        long o = (((long)chunk * BB + b) << 11) + (di << 4) + dso;
        *(float4*)&Pb[o]     = make_float4(P[0], P[1], P[2], P[3]);
        *(float4*)&Pb[o + 4] = make_float4(P[4], P[5], P[6], P[7]);
        *(float4*)&Sb[o]     = make_float4(h[0], h[1], h[2], h[3]);
        *(float4*)&Sb[o + 4] = make_float4(h[4], h[5], h[6], h[7]);
    }
}

// ---------------- scan phase 2 (stitch) ----------------
__global__ void k_scan_p2(float* Pb, const float* __restrict__ Sb) {
    int t = blockIdx.x * blockDim.x + threadIdx.x;
    int b = t >> 11;
    int s = t & 2047;
    float h = 0.f;
    for (int c = 0; c < NCHUNK; ++c) {
        long idx = (((long)c * BB + b) << 11) + s;
        float p = Pb[idx];
        float sv = Sb[idx];
        Pb[idx] = h;
        h = p * h + sv;
    }
}

// ------- scan phase 3 + gating + out_proj + residual + (optional) next in_proj -------
// Block = (chunk, b): full 128-di x 32-step chunk. Thread = (di, 8 ds-states).
__global__ __launch_bounds__(256, 1) void k_scan_p3_oi(
        const float* __restrict__ delta, const float* __restrict__ xi,
        const float* __restrict__ xdbc, const float* __restrict__ A_log,
        const float* __restrict__ Dp, const float* __restrict__ xz,
        const float* __restrict__ hin, const float* __restrict__ wTo,
        const float* __restrict__ wTi, float* __restrict__ tio,
        float* __restrict__ xz_out, int doB) {
    __shared__ __align__(16) float d_s[32 * 132];
    __shared__ __align__(16) float u_s[32 * 132];   // xi -> y -> gated
    __shared__ __align__(16) float bc_s[32 * 36];
    __shared__ __align__(16) float t_s[32 * 68];
    int chunk = blockIdx.x, b = blockIdx.y;
    int tid = threadIdx.x;
    long t0 = ((long)b << 12) + (long)chunk * CLEN;   // row base (== m0)

    // stage delta, xi, B/C
    for (int i = tid; i < 1024; i += 256) {
        int r = i >> 5, c4 = (i & 31) << 2;
        *(float4*)&d_s[r * 132 + c4] = *(const float4*)&delta[(t0 + r) * 128 + c4];
        *(float4*)&u_s[r * 132 + c4] = *(const float4*)&xi[(t0 + r) * 128 + c4];
    }
    {
        int r = tid >> 3, c4 = (tid & 7) << 2;
        *(float4*)&bc_s[r * 36 + c4] = *(const float4*)&xdbc[(t0 + r) * 36 + DTRK + c4];
    }

    int di = tid >> 1;
    int dso = (tid & 1) << 3;
    float4 al0 = *(const float4*)&A_log[(di << 4) + dso];
    float4 al1 = *(const float4*)&A_log[(di << 4) + dso + 4];
    float Av[8] = { -expf(al0.x), -expf(al0.y), -expf(al0.z), -expf(al0.w),
                    -expf(al1.x), -expf(al1.y), -expf(al1.z), -expf(al1.w) };
    float Dv = Dp[di];
    long o = (((long)chunk * BB + b) << 11) + (di << 4) + dso;
    float4 h0 = *(const float4*)&hin[o];
    float4 h1 = *(const float4*)&hin[o + 4];
    float h[8] = { h0.x, h0.y, h0.z, h0.w, h1.x, h1.y, h1.z, h1.w };
    __syncthreads();

    // 32-step scan, barrier-free (each wave touches only its own di range)
    #pragma unroll 4
    for (int i = 0; i < CLEN; ++i) {
        float d = d_s[i * 132 + di];
        float u = u_s[i * 132 + di];
        float du = d * u;
        const float* bc = &bc_s[i * 36];
        float4 B0 = *(const float4*)&bc[dso];
        float4 B1 = *(const float4*)&bc[dso + 4];
        float4 C0 = *(const float4*)&bc[16 + dso];
        float4 C1 = *(const float4*)&bc[16 + dso + 4];
        float a0 = __expf(d * Av[0]); h[0] = a0 * h[0] + du * B0.x;
        float a1 = __expf(d * Av[1]); h[1] = a1 * h[1] + du * B0.y;
        float a2 = __expf(d * Av[2]); h[2] = a2 * h[2] + du * B0.z;
        float a3 = __expf(d * Av[3]); h[3] = a3 * h[3] + du * B0.w;
        float a4 = __expf(d * Av[4]); h[4] = a4 * h[4] + du * B1.x;
        float a5 = __expf(d * Av[5]); h[5] = a5 * h[5] + du * B1.y;
        float a6 = __expf(d * Av[6]); h[6] = a6 * h[6] + du * B1.z;
        float a7 = __expf(d * Av[7]); h[7] = a7 * h[7] + du * B1.w;
        float yp = h[0] * C0.x + h[1] * C0.y + h[2] * C0.z + h[3] * C0.w
                 + h[4] * C1.x + h[5] * C1.y + h[6] * C1.z + h[7] * C1.w;
        yp += __shfl_xor(yp, 1);
        if (dso == 0)
            u_s[i * 132 + di] = yp + u * Dv;   // raw y (pre-gate)
    }
    __syncthreads();

    // gating pass: u_s = y * silu(z), vectorized
    for (int i = tid; i < 1024; i += 256) {
        int r = i >> 5, c4 = (i & 31) << 2;
        float4 y4 = *(float4*)&u_s[r * 132 + c4];
        float4 z4 = *(const float4*)&xz[((t0 + r) << 8) + DIM + c4];
        y4.x *= z4.x / (1.f + __expf(-z4.x));
        y4.y *= z4.y / (1.f + __expf(-z4.y));
        y4.z *= z4.z / (1.f + __expf(-z4.z));
        y4.w *= z4.w / (1.f + __expf(-z4.w));
        *(float4*)&u_s[r * 132 + c4] = y4;
    }
    __syncthreads();

    // out_proj + residual: 32 rows x 64 cols, K=128. thread = (rg 16 x 2 rows, 4 cols)
    {
        int rg = tid >> 4, cg = tid & 15;
        int n0 = cg << 2;
        float acc[2][4] = {};
        for (int k4 = 0; k4 < 32; ++k4) {
            float4 a0 = *(const float4*)&u_s[(rg << 1) * 132 + (k4 << 2)];
            float4 a1 = *(const float4*)&u_s[((rg << 1) + 1) * 132 + (k4 << 2)];
            #pragma unroll
            for (int kk = 0; kk < 4; ++kk) {
                const float* wr = wTo + (((k4 << 2) + kk) << 6) + n0;
                float4 w0 = *(const float4*)&wr[0];
                float av0 = (kk == 0) ? a0.x : (kk == 1) ? a0.y : (kk == 2) ? a0.z : a0.w;
                float av1 = (kk == 0) ? a1.x : (kk == 1) ? a1.y : (kk == 2) ? a1.z : a1.w;
                acc[0][0] += av0 * w0.x; acc[0][1] += av0 * w0.y;
                acc[0][2] += av0 * w0.z; acc[0][3] += av0 * w0.w;
                acc[1][0] += av1 * w0.x; acc[1][1] += av1 * w0.y;
                acc[1][2] += av1 * w0.z; acc[1][3] += av1 * w0.w;
            }
        }
        #pragma unroll
        for (int r2 = 0; r2 < 2; ++r2) {
            long m = t0 + (rg << 1) + r2;
            float4 tv = *(const float4*)&tio[(m << 6) + n0];
            tv.x += acc[r2][0]; tv.y += acc[r2][1];
            tv.z += acc[r2][2]; tv.w += acc[r2][3];
            *(float4*)&tio[(m << 6) + n0] = tv;
            *(float4*)&t_s[((rg << 1) + r2) * 68 + n0] = tv;
        }
    }
    if (!doB) return;
    __syncthreads();

    // in_proj (next layer): 32 rows x 256 cols, K=64. thread = (rg 8 x 4 rows, 8 cols)
    {
        int rg = tid >> 5, cgn = tid & 31;
        int n0 = cgn << 3;
        float acc[4][8] = {};
        for (int k4 = 0; k4 < 16; ++k4) {
            float4 a[4];
            #pragma unroll
            for (int r2 = 0; r2 < 4; ++r2)
                a[r2] = *(const float4*)&t_s[((rg << 2) + r2) * 68 + (k4 << 2)];
            #pragma unroll
            for (int kk = 0; kk < 4; ++kk) {
                const float* wr = wTi + (((k4 << 2) + kk) << 8) + n0;
                float4 w0 = *(const float4*)&wr[0];
                float4 w1 = *(const float4*)&wr[4];
                #pragma unroll
                for (int r2 = 0; r2 < 4; ++r2) {
                    float av = (kk == 0) ? a[r2].x : (kk == 1) ? a[r2].y
                             : (kk == 2) ? a[r2].z : a[r2].w;
                    acc[r2][0] += av * w0.x; acc[r2][1] += av * w0.y;
                    acc[r2][2] += av * w0.z; acc[r2][3] += av * w0.w;
                    acc[r2][4] += av * w1.x; acc[r2][5] += av * w1.y;
                    acc[r2][6] += av * w1.z; acc[r2][7] += av * w1.w;
                }
            }
        }
        #pragma unroll
        for (int r2 = 0; r2 < 4; ++r2) {
            long m = t0 + (rg << 2) + r2;
            *(float4*)&xz_out[(m << 8) + n0]     = make_float4(acc[r2][0], acc[r2][1], acc[r2][2], acc[r2][3]);
            *(float4*)&xz_out[(m << 8) + n0 + 4] = make_float4(acc[r2][4], acc[r2][5], acc[r2][6], acc[r2][7]);
        }
    }
}

// ---------------- decoder conv1 + fused BN-stat partials ----------------
__global__ __launch_bounds__(256, 1) void k_dec1_new(const float* __restrict__ tin,
                                                     const float* __restrict__ wT,
                                                     const float* __restrict__ bias,
                                                     float* __restrict__ out,
                                                     float* __restrict__ stats2) {
    __shared__ __align__(16) float x_s[64 * 132];
    __shared__ __align__(16) float w_s[4 * 4608];
    int tile = blockIdx.x;
    int b = blockIdx.y;
    int ty0 = (tile >> 3) << 3;
    int tx0 = (tile & 7) << 3;
    int tid = threadIdx.x;
    int wv = tid >> 6;
    int lane = tid & 63;
    int r = lane >> 3;
    int cg = lane & 7;

    for (int i = tid; i < 6400; i += 256) {
        int pl = i >> 6;
        int c = i & 63;
        int py = pl / 10, px = pl - py * 10;
        int ih = ty0 + py - 1, iw = tx0 + px - 1;
        float v = 0.f;
        if (ih >= 0 && ih < HH && iw >= 0 && iw < WWD)
            v = tin[(((long)((b << 12) + (ih << 6) + iw)) << 6) + c];
        x_s[c * 132 + py * 12 + px] = v;
    }
    float* myw = &w_s[wv * 4608];
    const float* gw = wT + (wv * 16) * 576;
    float4 pref[18];
    #pragma unroll
    for (int i = 0; i < 18; ++i)
        pref[i] = *(const float4*)&gw[(i * 64 + lane) * 4];
    #pragma unroll
    for (int i = 0; i < 18; ++i)
        *(float4*)&myw[(i * 64 + lane) * 4] = pref[i];
    __syncthreads();

    float acc[8][8] = {};
    #pragma unroll
    for (int ch = 0; ch < 2; ++ch) {
        if (ch == 0) {
            const float* gw1 = wT + (wv * 16 + 8) * 576;
            #pragma unroll
            for (int i = 0; i < 18; ++i)
                pref[i] = *(const float4*)&gw1[(i * 64 + lane) * 4];
        }
        for (int cl = 0; cl < 8; ++cl) {
            int cib = wv * 16 + ch * 8 + cl;
            float xrow[3][10];
            #pragma unroll
            for (int kh = 0; kh < 3; ++kh) {
                const float* xr = &x_s[cib * 132 + (r + kh) * 12];
                float4 a0 = *(const float4*)&xr[0];
                float4 a1 = *(const float4*)&xr[4];
                float2 a2 = *(const float2*)&xr[8];
                xrow[kh][0] = a0.x; xrow[kh][1] = a0.y; xrow[kh][2] = a0.z; xrow[kh][3] = a0.w;
                xrow[kh][4] = a1.x; xrow[kh][5] = a1.y; xrow[kh][6] = a1.z; xrow[kh][7] = a1.w;
                xrow[kh][8] = a2.x; xrow[kh][9] = a2.y;
            }
            const float* wp = &myw[cl * 576];
            #pragma unroll
            for (int kh = 0; kh < 3; ++kh) {
                #pragma unroll
                for (int kw = 0; kw < 3; ++kw) {
                    const float* wp2 = wp + (kh * 3 + kw) * 64 + (cg << 3);
                    float4 wa = *(const float4*)&wp2[0];
                    float4 wb = *(const float4*)&wp2[4];
                    #pragma unroll
                    for (int j = 0; j < 8; ++j) {
                        float xv = xrow[kh][kw + j];
                        acc[j][0] += xv * wa.x; acc[j][1] += xv * wa.y;
                        acc[j][2] += xv * wa.z; acc[j][3] += xv * wa.w;
                        acc[j][4] += xv * wb.x; acc[j][5] += xv * wb.y;
                        acc[j][6] += xv * wb.z; acc[j][7] += xv * wb.w;
                    }
                }
            }
        }
        if (ch == 0) {
            #pragma unroll
            for (int i = 0; i < 18; ++i)
                *(float4*)&myw[(i * 64 + lane) * 4] = pref[i];
        }
    }

    #pragma unroll
    for (int j = 0; j < 8; ++j) {
        *(float4*)&myw[lane * 68 + (j << 3)]     = make_float4(acc[j][0], acc[j][1], acc[j][2], acc[j][3]);
        *(float4*)&myw[lane * 68 + (j << 3) + 4] = make_float4(acc[j][4], acc[j][5], acc[j][6], acc[j][7]);
    }
    __syncthreads();

    float bv = bias[lane];
    float ssum = 0.f, ssq = 0.f;
    #pragma unroll
    for (int pp = 0; pp < 16; ++pp) {
        int pr = (wv << 1) + (pp >> 3);
        int pc = pp & 7;
        int ol = (pr << 3) + (lane >> 3);
        int ix = (pc << 3) + (lane & 7);
        float s = w_s[ol * 68 + ix] + w_s[4608 + ol * 68 + ix]
                + w_s[9216 + ol * 68 + ix] + w_s[13824 + ol * 68 + ix] + bv;
        out[(((long)((b << 12) + ((ty0 + pr) << 6) + tx0 + pc)) << 6) + lane] = s;
        ssum += s; ssq += s * s;
    }
    float* red = x_s;
    red[(wv << 6) + lane] = ssum;
    red[256 + (wv << 6) + lane] = ssq;
    __syncthreads();
    if (tid < 64) {
        float a = red[tid] + red[64 + tid] + red[128 + tid] + red[192 + tid];
        float q = red[256 + tid] + red[320 + tid] + red[384 + tid] + red[448 + tid];
        atomicAdd(&stats2[tid], a);
        atomicAdd(&stats2[64 + tid], q);
    }
}

// ------- decoder conv2 FUSED with BN+ReLU (inline stats) -------
__global__ void k_dec2_fused(const float* __restrict__ src, const float* __restrict__ stats2,
                             const float* __restrict__ g, const float* __restrict__ be,
                             const float* __restrict__ wT, const float* __restrict__ bias,
                             float* __restrict__ out) {
    __shared__ float x_s[64 * 101];
    __shared__ float w_s[64 * NFC * 12];
    __shared__ float sc_s[64];
    __shared__ float sh_s[64];
    int tile = blockIdx.x;
    int b = blockIdx.y;
    int ty0 = (tile >> 3) << 3;
    int tx0 = (tile & 7) << 3;
    int tid = threadIdx.x;

    if (tid < 64) {
        float m = stats2[tid] * (1.f / 16384.f);
        float var = stats2[64 + tid] * (1.f / 16384.f) - m * m;
        float s = g[tid] * rsqrtf(var + 1e-5f);
        sc_s[tid] = s;
        sh_s[tid] = be[tid] - m * s;
    }
    for (int i = tid; i < 64 * NFC * 12; i += 256)
        w_s[i] = wT[i];
    __syncthreads();

    for (int i = tid; i < 6400; i += 256) {
        int pl = i >> 6;
        int c = i & 63;
        int py = pl / 10, px = pl - py * 10;
        int ih = ty0 + py - 1, iw = tx0 + px - 1;
        float v = 0.f;
        if (ih >= 0 && ih < HH && iw >= 0 && iw < WWD) {
            v = src[((long)((b << 12) + (ih << 6) + iw)) * 64 + c];
            v = fmaxf(v * sc_s[c] + sh_s[c], 0.f);
        }
        x_s[c * 101 + pl] = v;
    }
    __syncthreads();

    int px = tid & 63;
    int py = px >> 3, pxx = px & 7;
    int cog = tid >> 6;
    float acc[3] = {0.f, 0.f, 0.f};
    int nco = (cog < 2) ? 3 : 2;

    for (int ci = 0; ci < 64; ++ci) {
        const float* xr = &x_s[ci * 101 + py * 10 + pxx];
        float xv[9];
        #pragma unroll
        for (int kh = 0; kh < 3; ++kh)
            #pragma unroll
            for (int kw = 0; kw < 3; ++kw)
                xv[kh * 3 + kw] = xr[kh * 10 + kw];
        #pragma unroll
        for (int j = 0; j < 3; ++j) {
            if (j >= nco) break;
            int co = cog + (j << 2);
            const float* wp = &w_s[(ci * NFC + co) * 12];
            float4 w0 = *(const float4*)&wp[0];
            float4 w1 = *(const float4*)&wp[4];
            float  w8 = wp[8];
            acc[j] += xv[0] * w0.x + xv[1] * w0.y + xv[2] * w0.z + xv[3] * w0.w
                    + xv[4] * w1.x + xv[5] * w1.y + xv[6] * w1.z + xv[7] * w1.w
                    + xv[8] * w8;
        }
    }
    int hw = ((ty0 + py) << 6) + tx0 + pxx;
    #pragma unroll
    for (int j = 0; j < 3; ++j) {
        if (j >= nco) break;
        int co = cog + (j << 2);
        out[((long)(b * NFC + co) << 12) + hw] = acc[j] + bias[co];
    }
}

extern "C" void kernel_launch(void* const* d_in, const int* in_sizes, int n_in,
                              void* d_out, int out_size, void* d_ws, size_t ws_size,
                              hipStream_t stream) {
    const float* x       = (const float*)d_in[0];
    const float* enc_w   = (const float*)d_in[1];
    const float* enc_b   = (const float*)d_in[2];
    const float* enc_g   = (const float*)d_in[3];
    const float* enc_be  = (const float*)d_in[4];
    const float* in_proj = (const float*)d_in[5];
    const float* conv_w  = (const float*)d_in[6];
    const float* conv_b  = (const float*)d_in[7];
    const float* x_proj  = (const float*)d_in[8];
    const float* dt_w    = (const float*)d_in[9];
    const float* dt_b    = (const float*)d_in[10];
    const float* A_log   = (const float*)d_in[11];
    const float* Dp      = (const float*)d_in[12];
    const float* out_prj = (const float*)d_in[13];
    const float* dec1_w  = (const float*)d_in[14];
    const float* dec1_b  = (const float*)d_in[15];
    const float* dec1_g  = (const float*)d_in[16];
    const float* dec1_be = (const float*)d_in[17];
    const float* dec2_w  = (const float*)d_in[18];
    const float* dec2_b  = (const float*)d_in[19];
    float* out = (float*)d_out;

    float* ws = (float*)d_ws;
    size_t off = 0;
    float* conv_buf  = ws + off; off += 1048576;  // enc/dec scratch; Pb during layers
    float* stats     = ws + off; off += 128;
    float* stats2    = ws + off; off += 128;
    float* wT1       = ws + off; off += 36864;
    float* wT2       = ws + off; off += 7680;
    float* wTin      = ws + off; off += 65536;
    float* wTout     = ws + off; off += 32768;
    float* t_buf     = ws + off; off += 1048576;
    float* xz_buf    = ws + off; off += 4194304;
    float* xi_buf    = ws + off; off += 2097152;
    float* xdbc_buf  = ws + off; off += 589824;
    float* delta_buf = ws + off; off += 2097152;
    float* Sb_buf    = ws + off; off += 1048576;
    (void)ws_size; (void)in_sizes; (void)n_in; (void)out_size;

    float* Pb = conv_buf;
    float* Sb = Sb_buf;

    // prep: transposes + zero stats (runs every launch; graph-safe)
    k_prep_all<<<560, 256, 0, stream>>>(in_proj, out_prj, dec1_w, dec2_w,
                                        wTin, wTout, wT1, wT2, stats, stats2);

    // encoder (BN-apply fused into first in_proj)
    k_enc_conv<<<4096, 256, 0, stream>>>(x, enc_w, enc_b, conv_buf, stats);

    // mamba layers
    k_gemm_in_bn<<<256, 256, 0, stream>>>(conv_buf, stats, enc_g, enc_be, wTin, t_buf, xz_buf);
    dim3 pg(NCHUNK, BB);
    for (int i = 0; i < NLAYER; ++i) {
        k_xproj_fused<<<512, 256, 0, stream>>>(xz_buf, conv_w + i * DIM * DCN,
                                               conv_b + i * DIM, x_proj + i * 36 * DIM,
                                               dt_w + i * DIM * DTRK, dt_b + i * DIM,
                                               A_log + i * DIM * DSN,
                                               xi_buf, xdbc_buf, delta_buf, Pb, Sb);
        k_scan_p2<<<32, 256, 0, stream>>>(Pb, Sb);
        int doB = (i < NLAYER - 1) ? 1 : 0;
        k_scan_p3_oi<<<pg, 256, 0, stream>>>(delta_buf, xi_buf, xdbc_buf,
                                             A_log + i * DIM * DSN, Dp + i * DIM,
                                             xz_buf, Pb, wTout + i * 8192,
                                             wTin + ((i + 1) & 3) * 16384,
                                             t_buf, xz_buf, doB);
    }

    // decoder
    dim3 dg1(64, BB);
    k_dec1_new<<<dg1, 256, 0, stream>>>(t_buf, wT1, dec1_b, conv_buf, stats2);
    k_dec2_fused<<<dg1, 256, 0, stream>>>(conv_buf, stats2, dec1_g, dec1_be, wT2, dec2_b, out);
}